// Round 14
// baseline (220.459 us; speedup 1.0000x reference)
//
#include <hip/hip_runtime.h>
#include <math.h>

#define NB    16      // batch
#define CDIM  256
#define COUT  144     // 64 q + 16 k + 64 v
#define MPIX  4096    // 64*64
#define SCOPE 23
#define PADH  11
#define BNEPS 1e-5f

typedef __attribute__((ext_vector_type(4))) float f32x4;
typedef __attribute__((ext_vector_type(8))) short s16x8;

__device__ __forceinline__ unsigned short f2bf(float f) {
    unsigned u = __builtin_bit_cast(unsigned, f);
    unsigned r = (u + 0x7FFFu + ((u >> 16) & 1u)) >> 16;
    return (unsigned short)r;
}

// ---------------- K0: both weight-fragment preps merged ----------------
__global__ void prep_frags(const float* __restrict__ w, const float* __restrict__ wl,
                           short* __restrict__ wqf, short* __restrict__ wfrag) {
    int i = blockIdx.x * 256 + threadIdx.x;
    if (i < 36864) {
        int j = i & 7, lane = (i >> 3) & 63;
        int fi = i >> 9;
        int mf = fi % 9, kc = fi / 9;
        int o = mf * 16 + (lane & 15);
        int c = kc * 32 + (lane >> 4) * 8 + j;
        wqf[i] = (short)f2bf(w[o * 256 + c]);
        return;
    }
    int i2 = i - 36864;
    if (i2 < 23 * 64 * 8) {
        int j = i2 & 7, l = (i2 >> 3) & 63, dy = i2 >> 9;
        int k = l & 15, t = ((l >> 4) << 3) + j;
        float wv = (t < SCOPE) ? wl[k * 529 + dy * 23 + t] : 0.f;
        wfrag[i2] = (short)f2bf(wv);
    }
}

// ---------------- K1: qkv = w_qkv @ x via bf16 MFMA ----------------
// q channels written TRANSPOSED [m][64c] f32 (block-exclusive m-slice); k,v linear.
__global__ void __launch_bounds__(256, 4) gemm_qkv(const float* __restrict__ x,
                                                   const short* __restrict__ wqf,
                                                   float* __restrict__ qkv) {
    __shared__ unsigned pk[16 * 65];
    int mt = blockIdx.x, b = blockIdx.y;
    int m0 = mt * 64;
    int tid = threadIdx.x;
    int px64 = tid & 63, c2b = tid >> 6;
    int lane = tid & 63, wv = tid >> 6;
    int pxl = lane & 15, kgq = lane >> 4;
    const float* xb = x + (size_t)b * CDIM * MPIX;
    float* qtb = qkv + (size_t)b * COUT * MPIX;   // q region, [m][64] layout
    const s16x8* wfv = (const s16x8*)wqf;

    f32x4 acc[9];
#pragma unroll
    for (int mf = 0; mf < 9; mf++) acc[mf] = 0.f;

#pragma unroll 1
    for (int kc = 0; kc < 8; kc++) {
        if (kc > 0) __syncthreads();
#pragma unroll
        for (int it = 0; it < 4; it++) {
            int c2 = c2b + it * 4;
            float x0 = xb[(size_t)(kc * 32 + 2 * c2) * MPIX + m0 + px64];
            float x1 = xb[(size_t)(kc * 32 + 2 * c2 + 1) * MPIX + m0 + px64];
            pk[c2 * 65 + px64] = (unsigned)f2bf(x0) | ((unsigned)f2bf(x1) << 16);
        }
        __syncthreads();
        const unsigned* bp = &pk[kgq * 4 * 65 + wv * 16 + pxl];
        int4 bi = make_int4(bp[0], bp[65], bp[130], bp[195]);
        s16x8 bf = __builtin_bit_cast(s16x8, bi);
#pragma unroll
        for (int mf = 0; mf < 9; mf++) {
            s16x8 af = wfv[(kc * 9 + mf) * 64 + lane];
            acc[mf] = __builtin_amdgcn_mfma_f32_16x16x32_bf16(af, bf, acc[mf], 0, 0, 0);
        }
    }

    int m = m0 + wv * 16 + pxl;
#pragma unroll
    for (int mf = 0; mf < 9; mf++) {
#pragma unroll
        for (int r = 0; r < 4; r++) {
            int o = mf * 16 + kgq * 4 + r;
            if (mf < 4) qtb[(size_t)m * 64 + o] = acc[mf][r];                  // q transposed
            else qkv[((size_t)b * COUT + o) * MPIX + m] = acc[mf][r];          // k,v linear
        }
    }
}

// ---------------- K2a: BN partial sums for q (transposed layout) ----------------
__global__ void stats_q(const float* __restrict__ qkv, float* __restrict__ qpart) {
    int mc = blockIdx.x, b = blockIdx.y;
    const float* qb = qkv + (size_t)b * COUT * MPIX;
    int tid = threadIdx.x;
    int c = tid & 63, mg = tid >> 6;
    float s = 0.f, s2 = 0.f;
#pragma unroll 4
    for (int i = 0; i < 64; i++) {
        int m = mc * 256 + i * 4 + mg;
        float v = qb[(size_t)m * 64 + c];
        s += v;
        s2 = fmaf(v, v, s2);
    }
    __shared__ float rs[4][64], rs2[4][64];
    rs[mg][c] = s;
    rs2[mg][c] = s2;
    __syncthreads();
    if (tid < 64) {
        float ts = rs[0][tid] + rs[1][tid] + rs[2][tid] + rs[3][tid];
        float ts2 = rs2[0][tid] + rs2[1][tid] + rs2[2][tid] + rs2[3][tid];
        qpart[(((size_t)tid * 16 + b) * 16 + mc) * 2 + 0] = ts;
        qpart[(((size_t)tid * 16 + b) * 16 + mc) * 2 + 1] = ts2;
    }
}

// ---------------- K2b: BN partial sums for v (linear layout) ----------------
__global__ void stats_v(const float* __restrict__ qkv, float* __restrict__ part) {
    int cx = blockIdx.x, b = blockIdx.y;
    const float* row = qkv + ((size_t)b * COUT + 80 + cx) * MPIX;
    int tid = threadIdx.x;
    float s = 0.f, s2 = 0.f;
    for (int i = tid; i < MPIX; i += 256) {
        float v = row[i];
        s += v;
        s2 = fmaf(v, v, s2);
    }
#pragma unroll
    for (int off = 32; off > 0; off >>= 1) {
        s += __shfl_down(s, off);
        s2 += __shfl_down(s2, off);
    }
    __shared__ float red[8];
    int wid = tid >> 6, lane = tid & 63;
    if (lane == 0) { red[wid * 2] = s; red[wid * 2 + 1] = s2; }
    __syncthreads();
    if (tid == 0) {
        float ts = 0.f, ts2 = 0.f;
#pragma unroll
        for (int w2 = 0; w2 < 4; w2++) { ts += red[w2 * 2]; ts2 += red[w2 * 2 + 1]; }
        part[(size_t)((64 + cx) * 16 + b) * 2 + 0] = ts;
        part[(size_t)((64 + cx) * 16 + b) * 2 + 1] = ts2;
    }
}

// ---------------- K3: finalize scale/shift ----------------
__global__ void stats_finalize(const float* __restrict__ part,
                               const float* __restrict__ qpart,
                               const float* __restrict__ gq, const float* __restrict__ bq,
                               const float* __restrict__ gv, const float* __restrict__ bv,
                               float* __restrict__ ascale, float* __restrict__ dshift) {
    int ch = threadIdx.x;
    if (ch >= 128) return;
    float s = 0.f, s2 = 0.f;
    if (ch < 64) {
        for (int i = 0; i < 256; i++) {
            s += qpart[((size_t)ch * 256 + i) * 2 + 0];
            s2 += qpart[((size_t)ch * 256 + i) * 2 + 1];
        }
    } else {
        for (int b = 0; b < 16; b++) {
            s += part[(size_t)(ch * 16 + b) * 2 + 0];
            s2 += part[(size_t)(ch * 16 + b) * 2 + 1];
        }
    }
    const float invN = 1.0f / 65536.0f;
    float mean = s * invN;
    float var = s2 * invN - mean * mean;
    float g = (ch < 64) ? gq[ch] : gv[ch - 64];
    float be = (ch < 64) ? bq[ch] : bv[ch - 64];
    float a = g * rsqrtf(var + BNEPS);
    ascale[ch] = a;
    dshift[ch] = be - mean * a;
}

// ---------------- K4: softmax over m for each (b, kc) ----------------
__global__ void softmax_k(const float* __restrict__ qkv, float* __restrict__ p) {
    int bk = blockIdx.x;
    int b = bk >> 4, kc = bk & 15;
    const float* row = qkv + ((size_t)b * COUT + 64 + kc) * MPIX;
    int tid = threadIdx.x;
    float v[16];
    float mx = -INFINITY;
#pragma unroll
    for (int i = 0; i < 16; i++) {
        v[i] = row[tid + i * 256];
        mx = fmaxf(mx, v[i]);
    }
#pragma unroll
    for (int off = 32; off > 0; off >>= 1) mx = fmaxf(mx, __shfl_down(mx, off));
    __shared__ float redm[4];
    __shared__ float bm;
    int wid = tid >> 6, lane = tid & 63;
    if (lane == 0) redm[wid] = mx;
    __syncthreads();
    if (tid == 0) bm = fmaxf(fmaxf(redm[0], redm[1]), fmaxf(redm[2], redm[3]));
    __syncthreads();
    mx = bm;
    float s = 0.f;
#pragma unroll
    for (int i = 0; i < 16; i++) {
        v[i] = expf(v[i] - mx);
        s += v[i];
    }
#pragma unroll
    for (int off = 32; off > 0; off >>= 1) s += __shfl_down(s, off);
    __shared__ float reds[4];
    __shared__ float bs;
    if (lane == 0) reds[wid] = s;
    __syncthreads();
    if (tid == 0) bs = reds[0] + reds[1] + reds[2] + reds[3];
    __syncthreads();
    float r = 1.0f / bs;
    float* prow = p + ((size_t)b * 16 + kc) * MPIX;
#pragma unroll
    for (int i = 0; i < 16; i++) prow[tid + i * 256] = v[i] * r;
}

// ---------------- K5: content lambda partials ----------------
__global__ void cl_partial(const float* __restrict__ qkv, const float* __restrict__ p,
                           const float* __restrict__ ascale, const float* __restrict__ dshift,
                           float* __restrict__ clpart) {
    __shared__ float vsT[128][65];
    int mc = blockIdx.x, b = blockIdx.y;
    int m0 = mc * 256;
    int tid = threadIdx.x;
    int vc = tid & 63, kg = tid >> 6;
    float acc[4] = {0.f, 0.f, 0.f, 0.f};
    for (int half = 0; half < 2; half++) {
        int mh = m0 + half * 128;
        __syncthreads();
        for (int i = tid; i < 64 * 128; i += 256) {
            int r = i >> 7, c = i & 127;
            vsT[c][r] = fmaf(ascale[64 + r], qkv[((size_t)b * COUT + 80 + r) * MPIX + mh + c],
                             dshift[64 + r]);
        }
        __syncthreads();
        for (int mm = 0; mm < 128; mm++) {
            float vv = vsT[mm][vc];
#pragma unroll
            for (int i = 0; i < 4; i++) {
                int kc = kg * 4 + i;
                acc[i] = fmaf(p[((size_t)b * 16 + kc) * MPIX + mh + mm], vv, acc[i]);
            }
        }
    }
#pragma unroll
    for (int i = 0; i < 4; i++) {
        int kc = kg * 4 + i;
        clpart[(((size_t)b * 16 + mc) * 16 + kc) * 64 + vc] = acc[i];
    }
}

__global__ void cl_reduce(const float* __restrict__ clpart, float* __restrict__ cl) {
    int b = blockIdx.x;
    for (int o = threadIdx.x; o < 1024; o += 256) {
        float s = 0.f;
        for (int mc = 0; mc < 16; mc++)
            s += clpart[((size_t)b * 16 + mc) * 1024 + o];
        cl[(size_t)b * 1024 + o] = s;
    }
}

// ---------------- K6: BN q + pack bf16 pairs, in place ----------------
__global__ void __launch_bounds__(256) bnq_t(float* __restrict__ qkv,
                                             const float* __restrict__ ascale,
                                             const float* __restrict__ dshift) {
    __shared__ float sv[64][65];   // [m][c]
    int mt = blockIdx.x, b = blockIdx.y;
    int m0 = mt * 64;
    float* qb = qkv + (size_t)b * COUT * MPIX;
    int tid = threadIdx.x;
    int c = tid & 63, mg = tid >> 6;
    float a = ascale[c], d = dshift[c];
#pragma unroll
    for (int i = 0; i < 16; i++) {
        int m = mg * 16 + i;
        sv[m][c] = fmaf(a, qb[(size_t)(m0 + m) * 64 + c], d);
    }
    __syncthreads();
    int m = tid >> 2, jb = (tid & 3) * 8;   // 8 dwords = 16 channels per thread
    unsigned dw[8];
#pragma unroll
    for (int j = 0; j < 8; j++) {
        int cc = jb * 2 + 2 * j;
        dw[j] = (unsigned)f2bf(sv[m][cc]) | ((unsigned)f2bf(sv[m][cc + 1]) << 16);
    }
    unsigned* dst = (unsigned*)qb + (size_t)(m0 + m) * 64 + jb;
    *(uint4*)dst = make_uint4(dw[0], dw[1], dw[2], dw[3]);
    *(uint4*)(dst + 4) = make_uint4(dw[4], dw[5], dw[6], dw[7]);
}

// ---------------- K8: fused MFMA conv + lambda epilogue (z-split, 8 blocks/CU) ----
// grid (64 vc, 16 b, 2 half), block 256, bounds(256,4) — KEEP the 128-reg tier
// (bound 8 spilled in R8); occupancy comes from the halved LDS (19KB -> 8 blocks/CU).
#define SPW 88
#define LD_FRAG(P) __builtin_bit_cast(s16x8, make_int4((P)[0], (P)[2], (P)[4], (P)[6]))
#define STEP(DY, J) do {                                                        \
    const unsigned* pnew_ = xbase + ((DY) + 3) * SPW;                           \
    rw[((J) + 3) & 3][0] = LD_FRAG(pnew_);                                      \
    rw[((J) + 3) & 3][1] = LD_FRAG(pnew_ + 16);                                 \
    int dyn_ = ((DY) + 7 < 22) ? (DY) + 7 : 22;                                 \
    wr[((J) + 7) & 7] = wf[dyn_ * 64 + lane];                                   \
    _Pragma("unroll")                                                           \
    for (int ty_ = 0; ty_ < 4; ty_++) {                                         \
      _Pragma("unroll")                                                         \
      for (int x2_ = 0; x2_ < 2; x2_++) {                                       \
        int t_ = ty_ * 2 + x2_;                                                 \
        acc[t_] = __builtin_amdgcn_mfma_f32_16x16x32_bf16(                      \
            wr[(J) & 7], rw[((J) + ty_) & 3][x2_], acc[t_], 0, 0, 0);           \
      }                                                                         \
    }                                                                           \
  } while (0)

__global__ void __launch_bounds__(256, 4) lambda_main(
    const float* __restrict__ qkv, const float* __restrict__ ascale,
    const float* __restrict__ dshift, const float* __restrict__ cl,
    const short* __restrict__ wfrag, const float* __restrict__ bl,
    float* __restrict__ out) {
    __shared__ unsigned spack[54 * SPW + 8];
    __shared__ float sck[16];

    int vc = blockIdx.x, b = blockIdx.y, h = blockIdx.z;
    int tid = threadIdx.x;

    if (tid < 16) sck[tid] = cl[((size_t)b * 16 + tid) * 64 + vc] + bl[tid];

    float av = ascale[64 + vc], dv = dshift[64 + vc];
    const float* vrow = qkv + ((size_t)b * COUT + 80 + vc) * MPIX;
    for (int i = tid; i < 54 * SPW; i += 256) {
        int y = i / SPW, e = i - y * SPW;
        int iy = h * 32 + y - PADH;
        float f0 = 0.f, f1 = 0.f;
        if ((unsigned)iy < 64u) {
            int ix0 = e - PADH, ix1 = e - PADH + 1;
            if ((unsigned)ix0 < 64u) f0 = fmaf(av, vrow[iy * 64 + ix0], dv);
            if ((unsigned)ix1 < 64u) f1 = fmaf(av, vrow[iy * 64 + ix1], dv);
        }
        spack[i] = (unsigned)f2bf(f0) | ((unsigned)f2bf(f1) << 16);
    }
    if (tid < 8) spack[54 * SPW + tid] = 0u;
    __syncthreads();

    int lane = tid & 63;
    int wv = tid >> 6;
    int px = lane & 15;
    int kg = lane >> 4;
    const s16x8* wf = (const s16x8*)wfrag;

    const unsigned* qtb = (const unsigned*)(qkv + (size_t)b * COUT * MPIX);  // bf16-packed q
    float* ob = out + (size_t)b * 256 * MPIX;

    float sck_l[4];
#pragma unroll
    for (int r = 0; r < 4; r++) sck_l[r] = sck[kg * 4 + r];

#pragma unroll 1
    for (int gg = 0; gg < 2; gg++) {
        int y0 = (gg * 4 + wv) * 4;            // local row base within this half
        const unsigned* base = &spack[y0 * SPW + px + kg * 8];

#pragma unroll 1
        for (int xh = 0; xh < 2; xh++) {
            const unsigned* xbase = base + xh * 32;
            f32x4 acc[8];
#pragma unroll
            for (int t = 0; t < 8; t++) acc[t] = 0.f;

            s16x8 rw[4][2];   // sliding 4-row window, slot = row & 3
            s16x8 wr[8];      // ring-8 weight prefetch
#pragma unroll
            for (int r0 = 0; r0 < 3; r0++) {
                const unsigned* p = xbase + r0 * SPW;
                rw[r0][0] = LD_FRAG(p);
                rw[r0][1] = LD_FRAG(p + 16);
            }
#pragma unroll
            for (int s = 0; s < 7; s++) wr[s] = wf[s * 64 + lane];

#pragma unroll 1
            for (int i8 = 0; i8 < 2; i8++) {
                int dyb = i8 * 8;
                STEP(dyb + 0, 0);
                STEP(dyb + 1, 1);
                STEP(dyb + 2, 2);
                STEP(dyb + 3, 3);
                STEP(dyb + 4, 4);
                STEP(dyb + 5, 5);
                STEP(dyb + 6, 6);
                STEP(dyb + 7, 7);
            }
            STEP(16, 0);
            STEP(17, 1);
            STEP(18, 2);
            STEP(19, 3);
            STEP(20, 4);
            STEP(21, 5);
            STEP(22, 6);

#pragma unroll
            for (int t = 0; t < 8; t++) {
                int ty = t >> 1, x2 = t & 1;
                int m0 = (h * 32 + y0 + ty) * 64 + (xh * 2 + x2) * 16;
                float lam[4];
#pragma unroll
                for (int r = 0; r < 4; r++) lam[r] = acc[t][r] + sck_l[r];
                const unsigned* qp = &qtb[(size_t)(m0 + px) * 64 + kg * 8];
                uint4 qa = *(const uint4*)qp;
                uint4 qb4 = *(const uint4*)(qp + 4);
                unsigned dws[8] = {qa.x, qa.y, qa.z, qa.w, qb4.x, qb4.y, qb4.z, qb4.w};
                float po[4] = {0.f, 0.f, 0.f, 0.f};
#pragma unroll
                for (int d = 0; d < 8; d++) {
                    float q0 = __builtin_bit_cast(float, dws[d] << 16);
                    float q1 = __builtin_bit_cast(float, dws[d] & 0xffff0000u);
                    int i0 = 2 * d, i1 = 2 * d + 1;
                    po[i0 & 3] = fmaf(q0, lam[i0 >> 2], po[i0 & 3]);
                    po[i1 & 3] = fmaf(q1, lam[i1 >> 2], po[i1 & 3]);
                }
#pragma unroll
                for (int n = 0; n < 4; n++) {
                    po[n] += __shfl_xor(po[n], 16);
                    po[n] += __shfl_xor(po[n], 32);
                }
                float sv = (kg == 0) ? po[0] : (kg == 1) ? po[1] : (kg == 2) ? po[2] : po[3];
                ob[(size_t)(kg * 64 + vc) * MPIX + m0 + px] = sv;
            }
        }
    }
}

// ---------------- launch ----------------
extern "C" void kernel_launch(void* const* d_in, const int* in_sizes, int n_in,
                              void* d_out, int out_size, void* d_ws, size_t ws_size,
                              hipStream_t stream) {
    const float* x      = (const float*)d_in[0];
    const float* w_qkv  = (const float*)d_in[1];
    const float* gq     = (const float*)d_in[2];
    const float* bq     = (const float*)d_in[3];
    const float* gv     = (const float*)d_in[4];
    const float* bv     = (const float*)d_in[5];
    const float* wl     = (const float*)d_in[6];
    const float* bl     = (const float*)d_in[7];
    float* out = (float*)d_out;

    float* ws     = (float*)d_ws;
    float* qkv    = ws;                    // 16*144*4096 = 9,437,184 (q region holds [m][64c])
    float* p      = qkv + 9437184;         // 1,048,576
    float* part   = p + 1048576;           // 4,096
    float* ascale = part + 4096;           // 128
    float* dshift = ascale + 128;          // 128
    float* clpart = dshift + 128;          // 262,144
    float* clb    = clpart + 262144;       // 16,384
    short* wfrag  = (short*)(clb + 16384); // 11,776 halfs
    short* wqf    = (short*)(clb + 16384 + 5888 + 64);  // 36,864 halfs
    float* qpart  = (float*)(wqf + 36864); // 32,768 floats

    prep_frags<<<190, 256, 0, stream>>>(w_qkv, wl, wqf, wfrag);
    gemm_qkv<<<dim3(64, 16), 256, 0, stream>>>(x, wqf, qkv);
    stats_q<<<dim3(16, 16), 256, 0, stream>>>(qkv, qpart);
    stats_v<<<dim3(64, 16), 256, 0, stream>>>(qkv, part);
    stats_finalize<<<1, 128, 0, stream>>>(part, qpart, gq, bq, gv, bv, ascale, dshift);
    softmax_k<<<256, 256, 0, stream>>>(qkv, p);
    cl_partial<<<dim3(16, 16), 256, 0, stream>>>(qkv, p, ascale, dshift, clpart);
    cl_reduce<<<16, 256, 0, stream>>>(clpart, clb);
    bnq_t<<<dim3(64, 16), 256, 0, stream>>>(qkv, ascale, dshift);
    lambda_main<<<dim3(64, 16, 2), 256, 0, stream>>>(qkv, ascale, dshift, clb, wfrag, bl, out);
}

// Round 15
// 215.811 us; speedup vs baseline: 1.0215x; 1.0215x over previous
//
#include <hip/hip_runtime.h>
#include <math.h>

#define NB    16      // batch
#define CDIM  256
#define COUT  144     // 64 q + 16 k + 64 v
#define MPIX  4096    // 64*64
#define SCOPE 23
#define PADH  11
#define BNEPS 1e-5f

typedef __attribute__((ext_vector_type(4))) float f32x4;
typedef __attribute__((ext_vector_type(8))) short s16x8;

__device__ __forceinline__ unsigned short f2bf(float f) {
    unsigned u = __builtin_bit_cast(unsigned, f);
    unsigned r = (u + 0x7FFFu + ((u >> 16) & 1u)) >> 16;
    return (unsigned short)r;
}

// ---------------- K0: both weight-fragment preps merged ----------------
__global__ void prep_frags(const float* __restrict__ w, const float* __restrict__ wl,
                           short* __restrict__ wqf, short* __restrict__ wfrag) {
    int i = blockIdx.x * 256 + threadIdx.x;
    if (i < 36864) {
        int j = i & 7, lane = (i >> 3) & 63;
        int fi = i >> 9;
        int mf = fi % 9, kc = fi / 9;
        int o = mf * 16 + (lane & 15);
        int c = kc * 32 + (lane >> 4) * 8 + j;
        wqf[i] = (short)f2bf(w[o * 256 + c]);
        return;
    }
    int i2 = i - 36864;
    if (i2 < 23 * 64 * 8) {
        int j = i2 & 7, l = (i2 >> 3) & 63, dy = i2 >> 9;
        int k = l & 15, t = ((l >> 4) << 3) + j;
        float wv = (t < SCOPE) ? wl[k * 529 + dy * 23 + t] : 0.f;
        wfrag[i2] = (short)f2bf(wv);
    }
}

// ---------------- K1: qkv = w_qkv @ x via bf16 MFMA ----------------
// q channels written TRANSPOSED [m][64c] f32 (block-exclusive m-slice); k,v linear.
__global__ void __launch_bounds__(256, 4) gemm_qkv(const float* __restrict__ x,
                                                   const short* __restrict__ wqf,
                                                   float* __restrict__ qkv) {
    __shared__ unsigned pk[16 * 65];
    int mt = blockIdx.x, b = blockIdx.y;
    int m0 = mt * 64;
    int tid = threadIdx.x;
    int px64 = tid & 63, c2b = tid >> 6;
    int lane = tid & 63, wv = tid >> 6;
    int pxl = lane & 15, kgq = lane >> 4;
    const float* xb = x + (size_t)b * CDIM * MPIX;
    float* qtb = qkv + (size_t)b * COUT * MPIX;   // q region, [m][64] layout
    const s16x8* wfv = (const s16x8*)wqf;

    f32x4 acc[9];
#pragma unroll
    for (int mf = 0; mf < 9; mf++) acc[mf] = 0.f;

#pragma unroll 1
    for (int kc = 0; kc < 8; kc++) {
        if (kc > 0) __syncthreads();
#pragma unroll
        for (int it = 0; it < 4; it++) {
            int c2 = c2b + it * 4;
            float x0 = xb[(size_t)(kc * 32 + 2 * c2) * MPIX + m0 + px64];
            float x1 = xb[(size_t)(kc * 32 + 2 * c2 + 1) * MPIX + m0 + px64];
            pk[c2 * 65 + px64] = (unsigned)f2bf(x0) | ((unsigned)f2bf(x1) << 16);
        }
        __syncthreads();
        const unsigned* bp = &pk[kgq * 4 * 65 + wv * 16 + pxl];
        int4 bi = make_int4(bp[0], bp[65], bp[130], bp[195]);
        s16x8 bf = __builtin_bit_cast(s16x8, bi);
#pragma unroll
        for (int mf = 0; mf < 9; mf++) {
            s16x8 af = wfv[(kc * 9 + mf) * 64 + lane];
            acc[mf] = __builtin_amdgcn_mfma_f32_16x16x32_bf16(af, bf, acc[mf], 0, 0, 0);
        }
    }

    int m = m0 + wv * 16 + pxl;
#pragma unroll
    for (int mf = 0; mf < 9; mf++) {
#pragma unroll
        for (int r = 0; r < 4; r++) {
            int o = mf * 16 + kgq * 4 + r;
            if (mf < 4) qtb[(size_t)m * 64 + o] = acc[mf][r];                  // q transposed
            else qkv[((size_t)b * COUT + o) * MPIX + m] = acc[mf][r];          // k,v linear
        }
    }
}

// ---------------- K2a: BN partial sums for q (transposed layout) ----------------
__global__ void stats_q(const float* __restrict__ qkv, float* __restrict__ qpart) {
    int mc = blockIdx.x, b = blockIdx.y;
    const float* qb = qkv + (size_t)b * COUT * MPIX;
    int tid = threadIdx.x;
    int c = tid & 63, mg = tid >> 6;
    float s = 0.f, s2 = 0.f;
#pragma unroll 4
    for (int i = 0; i < 64; i++) {
        int m = mc * 256 + i * 4 + mg;
        float v = qb[(size_t)m * 64 + c];
        s += v;
        s2 = fmaf(v, v, s2);
    }
    __shared__ float rs[4][64], rs2[4][64];
    rs[mg][c] = s;
    rs2[mg][c] = s2;
    __syncthreads();
    if (tid < 64) {
        float ts = rs[0][tid] + rs[1][tid] + rs[2][tid] + rs[3][tid];
        float ts2 = rs2[0][tid] + rs2[1][tid] + rs2[2][tid] + rs2[3][tid];
        qpart[(((size_t)tid * 16 + b) * 16 + mc) * 2 + 0] = ts;
        qpart[(((size_t)tid * 16 + b) * 16 + mc) * 2 + 1] = ts2;
    }
}

// ---------------- K2b: BN partial sums for v (linear layout) ----------------
__global__ void stats_v(const float* __restrict__ qkv, float* __restrict__ part) {
    int cx = blockIdx.x, b = blockIdx.y;
    const float* row = qkv + ((size_t)b * COUT + 80 + cx) * MPIX;
    int tid = threadIdx.x;
    float s = 0.f, s2 = 0.f;
    for (int i = tid; i < MPIX; i += 256) {
        float v = row[i];
        s += v;
        s2 = fmaf(v, v, s2);
    }
#pragma unroll
    for (int off = 32; off > 0; off >>= 1) {
        s += __shfl_down(s, off);
        s2 += __shfl_down(s2, off);
    }
    __shared__ float red[8];
    int wid = tid >> 6, lane = tid & 63;
    if (lane == 0) { red[wid * 2] = s; red[wid * 2 + 1] = s2; }
    __syncthreads();
    if (tid == 0) {
        float ts = 0.f, ts2 = 0.f;
#pragma unroll
        for (int w2 = 0; w2 < 4; w2++) { ts += red[w2 * 2]; ts2 += red[w2 * 2 + 1]; }
        part[(size_t)((64 + cx) * 16 + b) * 2 + 0] = ts;
        part[(size_t)((64 + cx) * 16 + b) * 2 + 1] = ts2;
    }
}

// ---------------- K3: finalize scale/shift ----------------
__global__ void stats_finalize(const float* __restrict__ part,
                               const float* __restrict__ qpart,
                               const float* __restrict__ gq, const float* __restrict__ bq,
                               const float* __restrict__ gv, const float* __restrict__ bv,
                               float* __restrict__ ascale, float* __restrict__ dshift) {
    int ch = threadIdx.x;
    if (ch >= 128) return;
    float s = 0.f, s2 = 0.f;
    if (ch < 64) {
        for (int i = 0; i < 256; i++) {
            s += qpart[((size_t)ch * 256 + i) * 2 + 0];
            s2 += qpart[((size_t)ch * 256 + i) * 2 + 1];
        }
    } else {
        for (int b = 0; b < 16; b++) {
            s += part[(size_t)(ch * 16 + b) * 2 + 0];
            s2 += part[(size_t)(ch * 16 + b) * 2 + 1];
        }
    }
    const float invN = 1.0f / 65536.0f;
    float mean = s * invN;
    float var = s2 * invN - mean * mean;
    float g = (ch < 64) ? gq[ch] : gv[ch - 64];
    float be = (ch < 64) ? bq[ch] : bv[ch - 64];
    float a = g * rsqrtf(var + BNEPS);
    ascale[ch] = a;
    dshift[ch] = be - mean * a;
}

// ---------------- K4: softmax over m for each (b, kc) ----------------
__global__ void softmax_k(const float* __restrict__ qkv, float* __restrict__ p) {
    int bk = blockIdx.x;
    int b = bk >> 4, kc = bk & 15;
    const float* row = qkv + ((size_t)b * COUT + 64 + kc) * MPIX;
    int tid = threadIdx.x;
    float v[16];
    float mx = -INFINITY;
#pragma unroll
    for (int i = 0; i < 16; i++) {
        v[i] = row[tid + i * 256];
        mx = fmaxf(mx, v[i]);
    }
#pragma unroll
    for (int off = 32; off > 0; off >>= 1) mx = fmaxf(mx, __shfl_down(mx, off));
    __shared__ float redm[4];
    __shared__ float bm;
    int wid = tid >> 6, lane = tid & 63;
    if (lane == 0) redm[wid] = mx;
    __syncthreads();
    if (tid == 0) bm = fmaxf(fmaxf(redm[0], redm[1]), fmaxf(redm[2], redm[3]));
    __syncthreads();
    mx = bm;
    float s = 0.f;
#pragma unroll
    for (int i = 0; i < 16; i++) {
        v[i] = expf(v[i] - mx);
        s += v[i];
    }
#pragma unroll
    for (int off = 32; off > 0; off >>= 1) s += __shfl_down(s, off);
    __shared__ float reds[4];
    __shared__ float bs;
    if (lane == 0) reds[wid] = s;
    __syncthreads();
    if (tid == 0) bs = reds[0] + reds[1] + reds[2] + reds[3];
    __syncthreads();
    float r = 1.0f / bs;
    float* prow = p + ((size_t)b * 16 + kc) * MPIX;
#pragma unroll
    for (int i = 0; i < 16; i++) prow[tid + i * 256] = v[i] * r;
}

// ---------------- K5: content lambda partials ----------------
__global__ void cl_partial(const float* __restrict__ qkv, const float* __restrict__ p,
                           const float* __restrict__ ascale, const float* __restrict__ dshift,
                           float* __restrict__ clpart) {
    __shared__ float vsT[128][65];
    int mc = blockIdx.x, b = blockIdx.y;
    int m0 = mc * 256;
    int tid = threadIdx.x;
    int vc = tid & 63, kg = tid >> 6;
    float acc[4] = {0.f, 0.f, 0.f, 0.f};
    for (int half = 0; half < 2; half++) {
        int mh = m0 + half * 128;
        __syncthreads();
        for (int i = tid; i < 64 * 128; i += 256) {
            int r = i >> 7, c = i & 127;
            vsT[c][r] = fmaf(ascale[64 + r], qkv[((size_t)b * COUT + 80 + r) * MPIX + mh + c],
                             dshift[64 + r]);
        }
        __syncthreads();
        for (int mm = 0; mm < 128; mm++) {
            float vv = vsT[mm][vc];
#pragma unroll
            for (int i = 0; i < 4; i++) {
                int kc = kg * 4 + i;
                acc[i] = fmaf(p[((size_t)b * 16 + kc) * MPIX + mh + mm], vv, acc[i]);
            }
        }
    }
#pragma unroll
    for (int i = 0; i < 4; i++) {
        int kc = kg * 4 + i;
        clpart[(((size_t)b * 16 + mc) * 16 + kc) * 64 + vc] = acc[i];
    }
}

__global__ void cl_reduce(const float* __restrict__ clpart, float* __restrict__ cl) {
    int b = blockIdx.x;
    for (int o = threadIdx.x; o < 1024; o += 256) {
        float s = 0.f;
        for (int mc = 0; mc < 16; mc++)
            s += clpart[((size_t)b * 16 + mc) * 1024 + o];
        cl[(size_t)b * 1024 + o] = s;
    }
}

// ---------------- K6: BN q + pack bf16 pairs, in place ----------------
__global__ void __launch_bounds__(256) bnq_t(float* __restrict__ qkv,
                                             const float* __restrict__ ascale,
                                             const float* __restrict__ dshift) {
    __shared__ float sv[64][65];   // [m][c]
    int mt = blockIdx.x, b = blockIdx.y;
    int m0 = mt * 64;
    float* qb = qkv + (size_t)b * COUT * MPIX;
    int tid = threadIdx.x;
    int c = tid & 63, mg = tid >> 6;
    float a = ascale[c], d = dshift[c];
#pragma unroll
    for (int i = 0; i < 16; i++) {
        int m = mg * 16 + i;
        sv[m][c] = fmaf(a, qb[(size_t)(m0 + m) * 64 + c], d);
    }
    __syncthreads();
    int m = tid >> 2, jb = (tid & 3) * 8;   // 8 dwords = 16 channels per thread
    unsigned dw[8];
#pragma unroll
    for (int j = 0; j < 8; j++) {
        int cc = jb * 2 + 2 * j;
        dw[j] = (unsigned)f2bf(sv[m][cc]) | ((unsigned)f2bf(sv[m][cc + 1]) << 16);
    }
    unsigned* dst = (unsigned*)qb + (size_t)(m0 + m) * 64 + jb;
    *(uint4*)dst = make_uint4(dw[0], dw[1], dw[2], dw[3]);
    *(uint4*)(dst + 4) = make_uint4(dw[4], dw[5], dw[6], dw[7]);
}

// ---------------- K8: fused MFMA conv + lambda epilogue ----------------
// R13 geometry (full 86-row image, grid 1024, bounds(256,4)) with consume-oldest
// STEP: read oldest row (ty=0) first, overwrite its slot with row DY+4 for the
// NEXT step (full-step latency slack; WAR is free — MFMA reads operands at issue).
// R9 ran this STEP but was confounded by the BN-fold epilogue; clean test here.
#define SPW 88
#define LD_FRAG(P) __builtin_bit_cast(s16x8, make_int4((P)[0], (P)[2], (P)[4], (P)[6]))
#define STEP(DY, J) do {                                                        \
    acc[0] = __builtin_amdgcn_mfma_f32_16x16x32_bf16(                           \
        wr[(J) & 7], rw[(J) & 3][0], acc[0], 0, 0, 0);                          \
    acc[1] = __builtin_amdgcn_mfma_f32_16x16x32_bf16(                           \
        wr[(J) & 7], rw[(J) & 3][1], acc[1], 0, 0, 0);                          \
    if ((DY) + 4 <= 25) {                                                       \
        const unsigned* pnew_ = xbase + ((DY) + 4) * SPW;                       \
        rw[(J) & 3][0] = LD_FRAG(pnew_);                                        \
        rw[(J) & 3][1] = LD_FRAG(pnew_ + 16);                                   \
    }                                                                           \
    int dyn_ = ((DY) + 7 < 22) ? (DY) + 7 : 22;                                 \
    wr[((J) + 7) & 7] = wf[dyn_ * 64 + lane];                                   \
    _Pragma("unroll")                                                           \
    for (int ty_ = 1; ty_ < 4; ty_++) {                                         \
      _Pragma("unroll")                                                         \
      for (int x2_ = 0; x2_ < 2; x2_++) {                                       \
        int t_ = ty_ * 2 + x2_;                                                 \
        acc[t_] = __builtin_amdgcn_mfma_f32_16x16x32_bf16(                      \
            wr[(J) & 7], rw[((J) + ty_) & 3][x2_], acc[t_], 0, 0, 0);           \
      }                                                                         \
    }                                                                           \
  } while (0)

__global__ void __launch_bounds__(256, 4) lambda_main(
    const float* __restrict__ qkv, const float* __restrict__ ascale,
    const float* __restrict__ dshift, const float* __restrict__ cl,
    const short* __restrict__ wfrag, const float* __restrict__ bl,
    float* __restrict__ out) {
    __shared__ unsigned spack[86 * SPW + 8];
    __shared__ float sck[16];

    int vc = blockIdx.x, b = blockIdx.y;
    int tid = threadIdx.x;

    if (tid < 16) sck[tid] = cl[((size_t)b * 16 + tid) * 64 + vc] + bl[tid];

    float av = ascale[64 + vc], dv = dshift[64 + vc];
    const float* vrow = qkv + ((size_t)b * COUT + 80 + vc) * MPIX;
    for (int i = tid; i < 86 * SPW; i += 256) {
        int y = i / SPW, e = i - y * SPW;
        int iy = y - PADH;
        float f0 = 0.f, f1 = 0.f;
        if ((unsigned)iy < 64u) {
            int ix0 = e - PADH, ix1 = e - PADH + 1;
            if ((unsigned)ix0 < 64u) f0 = fmaf(av, vrow[iy * 64 + ix0], dv);
            if ((unsigned)ix1 < 64u) f1 = fmaf(av, vrow[iy * 64 + ix1], dv);
        }
        spack[i] = (unsigned)f2bf(f0) | ((unsigned)f2bf(f1) << 16);
    }
    if (tid < 8) spack[86 * SPW + tid] = 0u;
    __syncthreads();

    int lane = tid & 63;
    int wv = tid >> 6;
    int px = lane & 15;
    int kg = lane >> 4;
    const s16x8* wf = (const s16x8*)wfrag;

    const unsigned* qtb = (const unsigned*)(qkv + (size_t)b * COUT * MPIX);  // bf16-packed q
    float* ob = out + (size_t)b * 256 * MPIX;

    float sck_l[4];
#pragma unroll
    for (int r = 0; r < 4; r++) sck_l[r] = sck[kg * 4 + r];

#pragma unroll 1
    for (int gg = 0; gg < 4; gg++) {
        int y0 = (gg * 4 + wv) * 4;
        const unsigned* base = &spack[y0 * SPW + px + kg * 8];

#pragma unroll 1
        for (int xh = 0; xh < 2; xh++) {
            const unsigned* xbase = base + xh * 32;
            f32x4 acc[8];
#pragma unroll
            for (int t = 0; t < 8; t++) acc[t] = 0.f;

            s16x8 rw[4][2];   // rows DY..DY+3 resident at step top
            s16x8 wr[8];      // ring-8 weight prefetch
#pragma unroll
            for (int r0 = 0; r0 < 4; r0++) {
                const unsigned* p = xbase + r0 * SPW;
                rw[r0][0] = LD_FRAG(p);
                rw[r0][1] = LD_FRAG(p + 16);
            }
#pragma unroll
            for (int s = 0; s < 7; s++) wr[s] = wf[s * 64 + lane];

#pragma unroll 1
            for (int i8 = 0; i8 < 2; i8++) {
                int dyb = i8 * 8;
                STEP(dyb + 0, 0);
                STEP(dyb + 1, 1);
                STEP(dyb + 2, 2);
                STEP(dyb + 3, 3);
                STEP(dyb + 4, 4);
                STEP(dyb + 5, 5);
                STEP(dyb + 6, 6);
                STEP(dyb + 7, 7);
            }
            STEP(16, 0);
            STEP(17, 1);
            STEP(18, 2);
            STEP(19, 3);
            STEP(20, 4);
            STEP(21, 5);
            STEP(22, 6);

#pragma unroll
            for (int t = 0; t < 8; t++) {
                int ty = t >> 1, x2 = t & 1;
                int m0 = (y0 + ty) * 64 + (xh * 2 + x2) * 16;
                float lam[4];
#pragma unroll
                for (int r = 0; r < 4; r++) lam[r] = acc[t][r] + sck_l[r];
                const unsigned* qp = &qtb[(size_t)(m0 + px) * 64 + kg * 8];
                uint4 qa = *(const uint4*)qp;
                uint4 qb4 = *(const uint4*)(qp + 4);
                unsigned dws[8] = {qa.x, qa.y, qa.z, qa.w, qb4.x, qb4.y, qb4.z, qb4.w};
                float po[4] = {0.f, 0.f, 0.f, 0.f};
#pragma unroll
                for (int d = 0; d < 8; d++) {
                    float q0 = __builtin_bit_cast(float, dws[d] << 16);
                    float q1 = __builtin_bit_cast(float, dws[d] & 0xffff0000u);
                    int i0 = 2 * d, i1 = 2 * d + 1;
                    po[i0 & 3] = fmaf(q0, lam[i0 >> 2], po[i0 & 3]);
                    po[i1 & 3] = fmaf(q1, lam[i1 >> 2], po[i1 & 3]);
                }
#pragma unroll
                for (int n = 0; n < 4; n++) {
                    po[n] += __shfl_xor(po[n], 16);
                    po[n] += __shfl_xor(po[n], 32);
                }
                float sv = (kg == 0) ? po[0] : (kg == 1) ? po[1] : (kg == 2) ? po[2] : po[3];
                ob[(size_t)(kg * 64 + vc) * MPIX + m0 + px] = sv;
            }
        }
    }
}

// ---------------- launch ----------------
extern "C" void kernel_launch(void* const* d_in, const int* in_sizes, int n_in,
                              void* d_out, int out_size, void* d_ws, size_t ws_size,
                              hipStream_t stream) {
    const float* x      = (const float*)d_in[0];
    const float* w_qkv  = (const float*)d_in[1];
    const float* gq     = (const float*)d_in[2];
    const float* bq     = (const float*)d_in[3];
    const float* gv     = (const float*)d_in[4];
    const float* bv     = (const float*)d_in[5];
    const float* wl     = (const float*)d_in[6];
    const float* bl     = (const float*)d_in[7];
    float* out = (float*)d_out;

    float* ws     = (float*)d_ws;
    float* qkv    = ws;                    // 16*144*4096 = 9,437,184 (q region holds [m][64c])
    float* p      = qkv + 9437184;         // 1,048,576
    float* part   = p + 1048576;           // 4,096
    float* ascale = part + 4096;           // 128
    float* dshift = ascale + 128;          // 128
    float* clpart = dshift + 128;          // 262,144
    float* clb    = clpart + 262144;       // 16,384
    short* wfrag  = (short*)(clb + 16384); // 11,776 halfs
    short* wqf    = (short*)(clb + 16384 + 5888 + 64);  // 36,864 halfs
    float* qpart  = (float*)(wqf + 36864); // 32,768 floats

    prep_frags<<<190, 256, 0, stream>>>(w_qkv, wl, wqf, wfrag);
    gemm_qkv<<<dim3(64, 16), 256, 0, stream>>>(x, wqf, qkv);
    stats_q<<<dim3(16, 16), 256, 0, stream>>>(qkv, qpart);
    stats_v<<<dim3(64, 16), 256, 0, stream>>>(qkv, part);
    stats_finalize<<<1, 128, 0, stream>>>(part, qpart, gq, bq, gv, bv, ascale, dshift);
    softmax_k<<<256, 256, 0, stream>>>(qkv, p);
    cl_partial<<<dim3(16, 16), 256, 0, stream>>>(qkv, p, ascale, dshift, clpart);
    cl_reduce<<<16, 256, 0, stream>>>(clpart, clb);
    bnq_t<<<dim3(64, 16), 256, 0, stream>>>(qkv, ascale, dshift);
    lambda_main<<<dim3(64, 16), 256, 0, stream>>>(qkv, ascale, dshift, clb, wfrag, bl, out);
}

// Round 16
// 208.688 us; speedup vs baseline: 1.0564x; 1.0341x over previous
//
#include <hip/hip_runtime.h>
#include <math.h>

#define NB    16      // batch
#define CDIM  256
#define COUT  144     // 64 q + 16 k + 64 v
#define MPIX  4096    // 64*64
#define SCOPE 23
#define PADH  11
#define BNEPS 1e-5f

typedef __attribute__((ext_vector_type(4))) float f32x4;
typedef __attribute__((ext_vector_type(8))) short s16x8;

__device__ __forceinline__ unsigned short f2bf(float f) {
    unsigned u = __builtin_bit_cast(unsigned, f);
    unsigned r = (u + 0x7FFFu + ((u >> 16) & 1u)) >> 16;
    return (unsigned short)r;
}

// ---------------- K0: both weight-fragment preps merged ----------------
__global__ void prep_frags(const float* __restrict__ w, const float* __restrict__ wl,
                           short* __restrict__ wqf, short* __restrict__ wfrag) {
    int i = blockIdx.x * 256 + threadIdx.x;
    if (i < 36864) {
        int j = i & 7, lane = (i >> 3) & 63;
        int fi = i >> 9;
        int mf = fi % 9, kc = fi / 9;
        int o = mf * 16 + (lane & 15);
        int c = kc * 32 + (lane >> 4) * 8 + j;
        wqf[i] = (short)f2bf(w[o * 256 + c]);
        return;
    }
    int i2 = i - 36864;
    if (i2 < 23 * 64 * 8) {
        int j = i2 & 7, l = (i2 >> 3) & 63, dy = i2 >> 9;
        int k = l & 15, t = ((l >> 4) << 3) + j;
        float wv = (t < SCOPE) ? wl[k * 529 + dy * 23 + t] : 0.f;
        wfrag[i2] = (short)f2bf(wv);
    }
}

// ---------------- K1: qkv = w_qkv @ x via bf16 MFMA ----------------
// q channels written TRANSPOSED [m][64c] f32 (block-exclusive m-slice); k,v linear.
__global__ void __launch_bounds__(256, 4) gemm_qkv(const float* __restrict__ x,
                                                   const short* __restrict__ wqf,
                                                   float* __restrict__ qkv) {
    __shared__ unsigned pk[16 * 65];
    int mt = blockIdx.x, b = blockIdx.y;
    int m0 = mt * 64;
    int tid = threadIdx.x;
    int px64 = tid & 63, c2b = tid >> 6;
    int lane = tid & 63, wv = tid >> 6;
    int pxl = lane & 15, kgq = lane >> 4;
    const float* xb = x + (size_t)b * CDIM * MPIX;
    float* qtb = qkv + (size_t)b * COUT * MPIX;   // q region, [m][64] layout
    const s16x8* wfv = (const s16x8*)wqf;

    f32x4 acc[9];
#pragma unroll
    for (int mf = 0; mf < 9; mf++) acc[mf] = 0.f;

#pragma unroll 1
    for (int kc = 0; kc < 8; kc++) {
        if (kc > 0) __syncthreads();
#pragma unroll
        for (int it = 0; it < 4; it++) {
            int c2 = c2b + it * 4;
            float x0 = xb[(size_t)(kc * 32 + 2 * c2) * MPIX + m0 + px64];
            float x1 = xb[(size_t)(kc * 32 + 2 * c2 + 1) * MPIX + m0 + px64];
            pk[c2 * 65 + px64] = (unsigned)f2bf(x0) | ((unsigned)f2bf(x1) << 16);
        }
        __syncthreads();
        const unsigned* bp = &pk[kgq * 4 * 65 + wv * 16 + pxl];
        int4 bi = make_int4(bp[0], bp[65], bp[130], bp[195]);
        s16x8 bf = __builtin_bit_cast(s16x8, bi);
#pragma unroll
        for (int mf = 0; mf < 9; mf++) {
            s16x8 af = wfv[(kc * 9 + mf) * 64 + lane];
            acc[mf] = __builtin_amdgcn_mfma_f32_16x16x32_bf16(af, bf, acc[mf], 0, 0, 0);
        }
    }

    int m = m0 + wv * 16 + pxl;
#pragma unroll
    for (int mf = 0; mf < 9; mf++) {
#pragma unroll
        for (int r = 0; r < 4; r++) {
            int o = mf * 16 + kgq * 4 + r;
            if (mf < 4) qtb[(size_t)m * 64 + o] = acc[mf][r];                  // q transposed
            else qkv[((size_t)b * COUT + o) * MPIX + m] = acc[mf][r];          // k,v linear
        }
    }
}

// ---------------- K2a: BN partial sums for q (transposed layout) ----------------
__global__ void stats_q(const float* __restrict__ qkv, float* __restrict__ qpart) {
    int mc = blockIdx.x, b = blockIdx.y;
    const float* qb = qkv + (size_t)b * COUT * MPIX;
    int tid = threadIdx.x;
    int c = tid & 63, mg = tid >> 6;
    float s = 0.f, s2 = 0.f;
#pragma unroll 4
    for (int i = 0; i < 64; i++) {
        int m = mc * 256 + i * 4 + mg;
        float v = qb[(size_t)m * 64 + c];
        s += v;
        s2 = fmaf(v, v, s2);
    }
    __shared__ float rs[4][64], rs2[4][64];
    rs[mg][c] = s;
    rs2[mg][c] = s2;
    __syncthreads();
    if (tid < 64) {
        float ts = rs[0][tid] + rs[1][tid] + rs[2][tid] + rs[3][tid];
        float ts2 = rs2[0][tid] + rs2[1][tid] + rs2[2][tid] + rs2[3][tid];
        qpart[(((size_t)tid * 16 + b) * 16 + mc) * 2 + 0] = ts;
        qpart[(((size_t)tid * 16 + b) * 16 + mc) * 2 + 1] = ts2;
    }
}

// ---------------- K2b: BN partial sums for v (linear layout) ----------------
__global__ void stats_v(const float* __restrict__ qkv, float* __restrict__ part) {
    int cx = blockIdx.x, b = blockIdx.y;
    const float* row = qkv + ((size_t)b * COUT + 80 + cx) * MPIX;
    int tid = threadIdx.x;
    float s = 0.f, s2 = 0.f;
    for (int i = tid; i < MPIX; i += 256) {
        float v = row[i];
        s += v;
        s2 = fmaf(v, v, s2);
    }
#pragma unroll
    for (int off = 32; off > 0; off >>= 1) {
        s += __shfl_down(s, off);
        s2 += __shfl_down(s2, off);
    }
    __shared__ float red[8];
    int wid = tid >> 6, lane = tid & 63;
    if (lane == 0) { red[wid * 2] = s; red[wid * 2 + 1] = s2; }
    __syncthreads();
    if (tid == 0) {
        float ts = 0.f, ts2 = 0.f;
#pragma unroll
        for (int w2 = 0; w2 < 4; w2++) { ts += red[w2 * 2]; ts2 += red[w2 * 2 + 1]; }
        part[(size_t)((64 + cx) * 16 + b) * 2 + 0] = ts;
        part[(size_t)((64 + cx) * 16 + b) * 2 + 1] = ts2;
    }
}

// ---------------- K3: finalize scale/shift ----------------
__global__ void stats_finalize(const float* __restrict__ part,
                               const float* __restrict__ qpart,
                               const float* __restrict__ gq, const float* __restrict__ bq,
                               const float* __restrict__ gv, const float* __restrict__ bv,
                               float* __restrict__ ascale, float* __restrict__ dshift) {
    int ch = threadIdx.x;
    if (ch >= 128) return;
    float s = 0.f, s2 = 0.f;
    if (ch < 64) {
        for (int i = 0; i < 256; i++) {
            s += qpart[((size_t)ch * 256 + i) * 2 + 0];
            s2 += qpart[((size_t)ch * 256 + i) * 2 + 1];
        }
    } else {
        for (int b = 0; b < 16; b++) {
            s += part[(size_t)(ch * 16 + b) * 2 + 0];
            s2 += part[(size_t)(ch * 16 + b) * 2 + 1];
        }
    }
    const float invN = 1.0f / 65536.0f;
    float mean = s * invN;
    float var = s2 * invN - mean * mean;
    float g = (ch < 64) ? gq[ch] : gv[ch - 64];
    float be = (ch < 64) ? bq[ch] : bv[ch - 64];
    float a = g * rsqrtf(var + BNEPS);
    ascale[ch] = a;
    dshift[ch] = be - mean * a;
}

// ---------------- K4: softmax over m for each (b, kc) ----------------
__global__ void softmax_k(const float* __restrict__ qkv, float* __restrict__ p) {
    int bk = blockIdx.x;
    int b = bk >> 4, kc = bk & 15;
    const float* row = qkv + ((size_t)b * COUT + 64 + kc) * MPIX;
    int tid = threadIdx.x;
    float v[16];
    float mx = -INFINITY;
#pragma unroll
    for (int i = 0; i < 16; i++) {
        v[i] = row[tid + i * 256];
        mx = fmaxf(mx, v[i]);
    }
#pragma unroll
    for (int off = 32; off > 0; off >>= 1) mx = fmaxf(mx, __shfl_down(mx, off));
    __shared__ float redm[4];
    __shared__ float bm;
    int wid = tid >> 6, lane = tid & 63;
    if (lane == 0) redm[wid] = mx;
    __syncthreads();
    if (tid == 0) bm = fmaxf(fmaxf(redm[0], redm[1]), fmaxf(redm[2], redm[3]));
    __syncthreads();
    mx = bm;
    float s = 0.f;
#pragma unroll
    for (int i = 0; i < 16; i++) {
        v[i] = expf(v[i] - mx);
        s += v[i];
    }
#pragma unroll
    for (int off = 32; off > 0; off >>= 1) s += __shfl_down(s, off);
    __shared__ float reds[4];
    __shared__ float bs;
    if (lane == 0) reds[wid] = s;
    __syncthreads();
    if (tid == 0) bs = reds[0] + reds[1] + reds[2] + reds[3];
    __syncthreads();
    float r = 1.0f / bs;
    float* prow = p + ((size_t)b * 16 + kc) * MPIX;
#pragma unroll
    for (int i = 0; i < 16; i++) prow[tid + i * 256] = v[i] * r;
}

// ---------------- K5: content lambda partials ----------------
__global__ void cl_partial(const float* __restrict__ qkv, const float* __restrict__ p,
                           const float* __restrict__ ascale, const float* __restrict__ dshift,
                           float* __restrict__ clpart) {
    __shared__ float vsT[128][65];
    int mc = blockIdx.x, b = blockIdx.y;
    int m0 = mc * 256;
    int tid = threadIdx.x;
    int vc = tid & 63, kg = tid >> 6;
    float acc[4] = {0.f, 0.f, 0.f, 0.f};
    for (int half = 0; half < 2; half++) {
        int mh = m0 + half * 128;
        __syncthreads();
        for (int i = tid; i < 64 * 128; i += 256) {
            int r = i >> 7, c = i & 127;
            vsT[c][r] = fmaf(ascale[64 + r], qkv[((size_t)b * COUT + 80 + r) * MPIX + mh + c],
                             dshift[64 + r]);
        }
        __syncthreads();
        for (int mm = 0; mm < 128; mm++) {
            float vv = vsT[mm][vc];
#pragma unroll
            for (int i = 0; i < 4; i++) {
                int kc = kg * 4 + i;
                acc[i] = fmaf(p[((size_t)b * 16 + kc) * MPIX + mh + mm], vv, acc[i]);
            }
        }
    }
#pragma unroll
    for (int i = 0; i < 4; i++) {
        int kc = kg * 4 + i;
        clpart[(((size_t)b * 16 + mc) * 16 + kc) * 64 + vc] = acc[i];
    }
}

__global__ void cl_reduce(const float* __restrict__ clpart, float* __restrict__ cl) {
    int b = blockIdx.x;
    for (int o = threadIdx.x; o < 1024; o += 256) {
        float s = 0.f;
        for (int mc = 0; mc < 16; mc++)
            s += clpart[((size_t)b * 16 + mc) * 1024 + o];
        cl[(size_t)b * 1024 + o] = s;
    }
}

// ---------------- K6: BN q + pack bf16 pairs, in place ----------------
__global__ void __launch_bounds__(256) bnq_t(float* __restrict__ qkv,
                                             const float* __restrict__ ascale,
                                             const float* __restrict__ dshift) {
    __shared__ float sv[64][65];   // [m][c]
    int mt = blockIdx.x, b = blockIdx.y;
    int m0 = mt * 64;
    float* qb = qkv + (size_t)b * COUT * MPIX;
    int tid = threadIdx.x;
    int c = tid & 63, mg = tid >> 6;
    float a = ascale[c], d = dshift[c];
#pragma unroll
    for (int i = 0; i < 16; i++) {
        int m = mg * 16 + i;
        sv[m][c] = fmaf(a, qb[(size_t)(m0 + m) * 64 + c], d);
    }
    __syncthreads();
    int m = tid >> 2, jb = (tid & 3) * 8;   // 8 dwords = 16 channels per thread
    unsigned dw[8];
#pragma unroll
    for (int j = 0; j < 8; j++) {
        int cc = jb * 2 + 2 * j;
        dw[j] = (unsigned)f2bf(sv[m][cc]) | ((unsigned)f2bf(sv[m][cc + 1]) << 16);
    }
    unsigned* dst = (unsigned*)qb + (size_t)(m0 + m) * 64 + jb;
    *(uint4*)dst = make_uint4(dw[0], dw[1], dw[2], dw[3]);
    *(uint4*)(dst + 4) = make_uint4(dw[4], dw[5], dw[6], dw[7]);
}

// ---------------- K8: fused MFMA conv + lambda epilogue ----------------
// z-split (54-row half-image, 19KB LDS, grid 2048) + wr ring 8->4 (-16 VGPR):
// target combined VGPR+AGPR <= ~84 -> 6 waves/SIMD if allocation granule is fine.
// STEP = R13's proven schedule (row DY+3 into slot (J+3)&3; weight DY+3 ring-4).
#define SPW 88
#define LD_FRAG(P) __builtin_bit_cast(s16x8, make_int4((P)[0], (P)[2], (P)[4], (P)[6]))
#define STEP(DY, J) do {                                                        \
    const unsigned* pnew_ = xbase + ((DY) + 3) * SPW;                           \
    rw[((J) + 3) & 3][0] = LD_FRAG(pnew_);                                      \
    rw[((J) + 3) & 3][1] = LD_FRAG(pnew_ + 16);                                 \
    int dyn_ = ((DY) + 3 < 22) ? (DY) + 3 : 22;                                 \
    wr[((J) + 3) & 3] = wf[dyn_ * 64 + lane];                                   \
    _Pragma("unroll")                                                           \
    for (int ty_ = 0; ty_ < 4; ty_++) {                                         \
      _Pragma("unroll")                                                         \
      for (int x2_ = 0; x2_ < 2; x2_++) {                                       \
        int t_ = ty_ * 2 + x2_;                                                 \
        acc[t_] = __builtin_amdgcn_mfma_f32_16x16x32_bf16(                      \
            wr[(J) & 3], rw[((J) + ty_) & 3][x2_], acc[t_], 0, 0, 0);           \
      }                                                                         \
    }                                                                           \
  } while (0)

__global__ void __launch_bounds__(256, 4) lambda_main(
    const float* __restrict__ qkv, const float* __restrict__ ascale,
    const float* __restrict__ dshift, const float* __restrict__ cl,
    const short* __restrict__ wfrag, const float* __restrict__ bl,
    float* __restrict__ out) {
    __shared__ unsigned spack[54 * SPW + 8];
    __shared__ float sck[16];

    int vc = blockIdx.x, b = blockIdx.y, h = blockIdx.z;
    int tid = threadIdx.x;

    if (tid < 16) sck[tid] = cl[((size_t)b * 16 + tid) * 64 + vc] + bl[tid];

    float av = ascale[64 + vc], dv = dshift[64 + vc];
    const float* vrow = qkv + ((size_t)b * COUT + 80 + vc) * MPIX;
    for (int i = tid; i < 54 * SPW; i += 256) {
        int y = i / SPW, e = i - y * SPW;
        int iy = h * 32 + y - PADH;
        float f0 = 0.f, f1 = 0.f;
        if ((unsigned)iy < 64u) {
            int ix0 = e - PADH, ix1 = e - PADH + 1;
            if ((unsigned)ix0 < 64u) f0 = fmaf(av, vrow[iy * 64 + ix0], dv);
            if ((unsigned)ix1 < 64u) f1 = fmaf(av, vrow[iy * 64 + ix1], dv);
        }
        spack[i] = (unsigned)f2bf(f0) | ((unsigned)f2bf(f1) << 16);
    }
    if (tid < 8) spack[54 * SPW + tid] = 0u;
    __syncthreads();

    int lane = tid & 63;
    int wv = tid >> 6;
    int px = lane & 15;
    int kg = lane >> 4;
    const s16x8* wf = (const s16x8*)wfrag;

    const unsigned* qtb = (const unsigned*)(qkv + (size_t)b * COUT * MPIX);  // bf16-packed q
    float* ob = out + (size_t)b * 256 * MPIX;

    float sck_l[4];
#pragma unroll
    for (int r = 0; r < 4; r++) sck_l[r] = sck[kg * 4 + r];

#pragma unroll 1
    for (int gg = 0; gg < 2; gg++) {
        int y0 = (gg * 4 + wv) * 4;            // local row base within this half
        const unsigned* base = &spack[y0 * SPW + px + kg * 8];

#pragma unroll 1
        for (int xh = 0; xh < 2; xh++) {
            const unsigned* xbase = base + xh * 32;
            f32x4 acc[8];
#pragma unroll
            for (int t = 0; t < 8; t++) acc[t] = 0.f;

            s16x8 rw[4][2];   // sliding 4-row window, slot = row & 3
            s16x8 wr[4];      // ring-4 weight prefetch (weights are L1-resident)
#pragma unroll
            for (int r0 = 0; r0 < 3; r0++) {
                const unsigned* p = xbase + r0 * SPW;
                rw[r0][0] = LD_FRAG(p);
                rw[r0][1] = LD_FRAG(p + 16);
            }
#pragma unroll
            for (int s = 0; s < 3; s++) wr[s] = wf[s * 64 + lane];

#pragma unroll 1
            for (int i8 = 0; i8 < 2; i8++) {
                int dyb = i8 * 8;
                STEP(dyb + 0, 0);
                STEP(dyb + 1, 1);
                STEP(dyb + 2, 2);
                STEP(dyb + 3, 3);
                STEP(dyb + 4, 4);
                STEP(dyb + 5, 5);
                STEP(dyb + 6, 6);
                STEP(dyb + 7, 7);
            }
            STEP(16, 0);
            STEP(17, 1);
            STEP(18, 2);
            STEP(19, 3);
            STEP(20, 4);
            STEP(21, 5);
            STEP(22, 6);

#pragma unroll
            for (int t = 0; t < 8; t++) {
                int ty = t >> 1, x2 = t & 1;
                int m0 = (h * 32 + y0 + ty) * 64 + (xh * 2 + x2) * 16;
                float lam[4];
#pragma unroll
                for (int r = 0; r < 4; r++) lam[r] = acc[t][r] + sck_l[r];
                const unsigned* qp = &qtb[(size_t)(m0 + px) * 64 + kg * 8];
                uint4 qa = *(const uint4*)qp;
                uint4 qb4 = *(const uint4*)(qp + 4);
                unsigned dws[8] = {qa.x, qa.y, qa.z, qa.w, qb4.x, qb4.y, qb4.z, qb4.w};
                float po[4] = {0.f, 0.f, 0.f, 0.f};
#pragma unroll
                for (int d = 0; d < 8; d++) {
                    float q0 = __builtin_bit_cast(float, dws[d] << 16);
                    float q1 = __builtin_bit_cast(float, dws[d] & 0xffff0000u);
                    int i0 = 2 * d, i1 = 2 * d + 1;
                    po[i0 & 3] = fmaf(q0, lam[i0 >> 2], po[i0 & 3]);
                    po[i1 & 3] = fmaf(q1, lam[i1 >> 2], po[i1 & 3]);
                }
#pragma unroll
                for (int n = 0; n < 4; n++) {
                    po[n] += __shfl_xor(po[n], 16);
                    po[n] += __shfl_xor(po[n], 32);
                }
                float sv = (kg == 0) ? po[0] : (kg == 1) ? po[1] : (kg == 2) ? po[2] : po[3];
                ob[(size_t)(kg * 64 + vc) * MPIX + m0 + px] = sv;
            }
        }
    }
}

// ---------------- launch ----------------
extern "C" void kernel_launch(void* const* d_in, const int* in_sizes, int n_in,
                              void* d_out, int out_size, void* d_ws, size_t ws_size,
                              hipStream_t stream) {
    const float* x      = (const float*)d_in[0];
    const float* w_qkv  = (const float*)d_in[1];
    const float* gq     = (const float*)d_in[2];
    const float* bq     = (const float*)d_in[3];
    const float* gv     = (const float*)d_in[4];
    const float* bv     = (const float*)d_in[5];
    const float* wl     = (const float*)d_in[6];
    const float* bl     = (const float*)d_in[7];
    float* out = (float*)d_out;

    float* ws     = (float*)d_ws;
    float* qkv    = ws;                    // 16*144*4096 = 9,437,184 (q region holds [m][64c])
    float* p      = qkv + 9437184;         // 1,048,576
    float* part   = p + 1048576;           // 4,096
    float* ascale = part + 4096;           // 128
    float* dshift = ascale + 128;          // 128
    float* clpart = dshift + 128;          // 262,144
    float* clb    = clpart + 262144;       // 16,384
    short* wfrag  = (short*)(clb + 16384); // 11,776 halfs
    short* wqf    = (short*)(clb + 16384 + 5888 + 64);  // 36,864 halfs
    float* qpart  = (float*)(wqf + 36864); // 32,768 floats

    prep_frags<<<190, 256, 0, stream>>>(w_qkv, wl, wqf, wfrag);
    gemm_qkv<<<dim3(64, 16), 256, 0, stream>>>(x, wqf, qkv);
    stats_q<<<dim3(16, 16), 256, 0, stream>>>(qkv, qpart);
    stats_v<<<dim3(64, 16), 256, 0, stream>>>(qkv, part);
    stats_finalize<<<1, 128, 0, stream>>>(part, qpart, gq, bq, gv, bv, ascale, dshift);
    softmax_k<<<256, 256, 0, stream>>>(qkv, p);
    cl_partial<<<dim3(16, 16), 256, 0, stream>>>(qkv, p, ascale, dshift, clpart);
    cl_reduce<<<16, 256, 0, stream>>>(clpart, clb);
    bnq_t<<<dim3(64, 16), 256, 0, stream>>>(qkv, ascale, dshift);
    lambda_main<<<dim3(64, 16, 2), 256, 0, stream>>>(qkv, ascale, dshift, clb, wfrag, bl, out);
}

// Round 17
// 202.092 us; speedup vs baseline: 1.0909x; 1.0326x over previous
//
#include <hip/hip_runtime.h>
#include <math.h>

#define NB    16      // batch
#define CDIM  256
#define COUT  144     // 64 q + 16 k + 64 v
#define MPIX  4096    // 64*64
#define SCOPE 23
#define PADH  11
#define BNEPS 1e-5f

typedef __attribute__((ext_vector_type(4))) float f32x4;
typedef __attribute__((ext_vector_type(8))) short s16x8;

__device__ __forceinline__ unsigned short f2bf(float f) {
    unsigned u = __builtin_bit_cast(unsigned, f);
    unsigned r = (u + 0x7FFFu + ((u >> 16) & 1u)) >> 16;
    return (unsigned short)r;
}

// ---------------- K0: both weight-fragment preps merged ----------------
__global__ void prep_frags(const float* __restrict__ w, const float* __restrict__ wl,
                           short* __restrict__ wqf, short* __restrict__ wfrag) {
    int i = blockIdx.x * 256 + threadIdx.x;
    if (i < 36864) {
        int j = i & 7, lane = (i >> 3) & 63;
        int fi = i >> 9;
        int mf = fi % 9, kc = fi / 9;
        int o = mf * 16 + (lane & 15);
        int c = kc * 32 + (lane >> 4) * 8 + j;
        wqf[i] = (short)f2bf(w[o * 256 + c]);
        return;
    }
    int i2 = i - 36864;
    if (i2 < 23 * 64 * 8) {
        int j = i2 & 7, l = (i2 >> 3) & 63, dy = i2 >> 9;
        int k = l & 15, t = ((l >> 4) << 3) + j;
        float wv = (t < SCOPE) ? wl[k * 529 + dy * 23 + t] : 0.f;
        wfrag[i2] = (short)f2bf(wv);
    }
}

// ---------------- K1: qkv = w_qkv @ x via bf16 MFMA + fused BN stat partials ------
// q channels written TRANSPOSED [m][64c] f32 (block-exclusive m-slice); k,v linear.
// Per-block (sum,sumsq) over its 64 pixels for ALL 144 channels -> statpart[ch][b][mt].
__global__ void __launch_bounds__(256, 4) gemm_qkv(const float* __restrict__ x,
                                                   const short* __restrict__ wqf,
                                                   float* __restrict__ qkv,
                                                   float* __restrict__ statpart) {
    __shared__ unsigned pk[16 * 65];
    __shared__ float ssum[4][144], ssq[4][144];
    int mt = blockIdx.x, b = blockIdx.y;
    int m0 = mt * 64;
    int tid = threadIdx.x;
    int px64 = tid & 63, c2b = tid >> 6;
    int lane = tid & 63, wv = tid >> 6;
    int pxl = lane & 15, kgq = lane >> 4;
    const float* xb = x + (size_t)b * CDIM * MPIX;
    float* qtb = qkv + (size_t)b * COUT * MPIX;   // q region, [m][64] layout
    const s16x8* wfv = (const s16x8*)wqf;

    f32x4 acc[9];
#pragma unroll
    for (int mf = 0; mf < 9; mf++) acc[mf] = 0.f;

#pragma unroll 1
    for (int kc = 0; kc < 8; kc++) {
        if (kc > 0) __syncthreads();
#pragma unroll
        for (int it = 0; it < 4; it++) {
            int c2 = c2b + it * 4;
            float x0 = xb[(size_t)(kc * 32 + 2 * c2) * MPIX + m0 + px64];
            float x1 = xb[(size_t)(kc * 32 + 2 * c2 + 1) * MPIX + m0 + px64];
            pk[c2 * 65 + px64] = (unsigned)f2bf(x0) | ((unsigned)f2bf(x1) << 16);
        }
        __syncthreads();
        const unsigned* bp = &pk[kgq * 4 * 65 + wv * 16 + pxl];
        int4 bi = make_int4(bp[0], bp[65], bp[130], bp[195]);
        s16x8 bf = __builtin_bit_cast(s16x8, bi);
#pragma unroll
        for (int mf = 0; mf < 9; mf++) {
            s16x8 af = wfv[(kc * 9 + mf) * 64 + lane];
            acc[mf] = __builtin_amdgcn_mfma_f32_16x16x32_bf16(af, bf, acc[mf], 0, 0, 0);
        }
    }

    int m = m0 + wv * 16 + pxl;
#pragma unroll
    for (int mf = 0; mf < 9; mf++) {
#pragma unroll
        for (int r = 0; r < 4; r++) {
            int o = mf * 16 + kgq * 4 + r;
            if (mf < 4) qtb[(size_t)m * 64 + o] = acc[mf][r];                  // q transposed
            else qkv[((size_t)b * COUT + o) * MPIX + m] = acc[mf][r];          // k,v linear
        }
    }

    // fused stats: reduce over the 16 px-lanes of each kgq group, then over 4 waves
#pragma unroll
    for (int mf = 0; mf < 9; mf++) {
#pragma unroll
        for (int r = 0; r < 4; r++) {
            float s = acc[mf][r];
            float s2 = s * s;
#pragma unroll
            for (int off = 1; off < 16; off <<= 1) {
                s += __shfl_xor(s, off);
                s2 += __shfl_xor(s2, off);
            }
            if (pxl == 0) {
                int ch = mf * 16 + kgq * 4 + r;
                ssum[wv][ch] = s;
                ssq[wv][ch] = s2;
            }
        }
    }
    __syncthreads();
    if (tid < 144) {
        float s = ssum[0][tid] + ssum[1][tid] + ssum[2][tid] + ssum[3][tid];
        float s2 = ssq[0][tid] + ssq[1][tid] + ssq[2][tid] + ssq[3][tid];
        size_t idx = (((size_t)tid * 16 + b) * 64 + mt) * 2;
        statpart[idx + 0] = s;
        statpart[idx + 1] = s2;
    }
}

// ---------------- K3: finalize scale/shift (grid 128 blocks, one stat-channel each) ----
__global__ void stats_finalize(const float* __restrict__ statpart,
                               const float* __restrict__ gq, const float* __restrict__ bq,
                               const float* __restrict__ gv, const float* __restrict__ bv,
                               float* __restrict__ ascale, float* __restrict__ dshift) {
    int sch = blockIdx.x;                         // 0..127 stat channel
    int gch = (sch < 64) ? sch : sch + 16;        // gemm channel (skip k 64..79)
    const float* sp = statpart + (size_t)gch * 1024 * 2;
    int tid = threadIdx.x;
    float s = 0.f, s2 = 0.f;
    for (int i = tid; i < 1024; i += 256) {
        s += sp[i * 2 + 0];
        s2 += sp[i * 2 + 1];
    }
#pragma unroll
    for (int off = 32; off > 0; off >>= 1) {
        s += __shfl_down(s, off);
        s2 += __shfl_down(s2, off);
    }
    __shared__ float red[8];
    int wid = tid >> 6, lane = tid & 63;
    if (lane == 0) { red[wid * 2] = s; red[wid * 2 + 1] = s2; }
    __syncthreads();
    if (tid == 0) {
        float ts = 0.f, ts2 = 0.f;
#pragma unroll
        for (int w2 = 0; w2 < 4; w2++) { ts += red[w2 * 2]; ts2 += red[w2 * 2 + 1]; }
        const float invN = 1.0f / 65536.0f;
        float mean = ts * invN;
        float var = ts2 * invN - mean * mean;
        float g = (sch < 64) ? gq[sch] : gv[sch - 64];
        float be = (sch < 64) ? bq[sch] : bv[sch - 64];
        float a = g * rsqrtf(var + BNEPS);
        ascale[sch] = a;
        dshift[sch] = be - mean * a;
    }
}

// ---------------- K4: softmax over m for each (b, kc) ----------------
__global__ void softmax_k(const float* __restrict__ qkv, float* __restrict__ p) {
    int bk = blockIdx.x;
    int b = bk >> 4, kc = bk & 15;
    const float* row = qkv + ((size_t)b * COUT + 64 + kc) * MPIX;
    int tid = threadIdx.x;
    float v[16];
    float mx = -INFINITY;
#pragma unroll
    for (int i = 0; i < 16; i++) {
        v[i] = row[tid + i * 256];
        mx = fmaxf(mx, v[i]);
    }
#pragma unroll
    for (int off = 32; off > 0; off >>= 1) mx = fmaxf(mx, __shfl_down(mx, off));
    __shared__ float redm[4];
    __shared__ float bm;
    int wid = tid >> 6, lane = tid & 63;
    if (lane == 0) redm[wid] = mx;
    __syncthreads();
    if (tid == 0) bm = fmaxf(fmaxf(redm[0], redm[1]), fmaxf(redm[2], redm[3]));
    __syncthreads();
    mx = bm;
    float s = 0.f;
#pragma unroll
    for (int i = 0; i < 16; i++) {
        v[i] = expf(v[i] - mx);
        s += v[i];
    }
#pragma unroll
    for (int off = 32; off > 0; off >>= 1) s += __shfl_down(s, off);
    __shared__ float reds[4];
    __shared__ float bs;
    if (lane == 0) reds[wid] = s;
    __syncthreads();
    if (tid == 0) bs = reds[0] + reds[1] + reds[2] + reds[3];
    __syncthreads();
    float r = 1.0f / bs;
    float* prow = p + ((size_t)b * 16 + kc) * MPIX;
#pragma unroll
    for (int i = 0; i < 16; i++) prow[tid + i * 256] = v[i] * r;
}

// ---------------- K5: content lambda partials ----------------
__global__ void cl_partial(const float* __restrict__ qkv, const float* __restrict__ p,
                           const float* __restrict__ ascale, const float* __restrict__ dshift,
                           float* __restrict__ clpart) {
    __shared__ float vsT[128][65];
    int mc = blockIdx.x, b = blockIdx.y;
    int m0 = mc * 256;
    int tid = threadIdx.x;
    int vc = tid & 63, kg = tid >> 6;
    float acc[4] = {0.f, 0.f, 0.f, 0.f};
    for (int half = 0; half < 2; half++) {
        int mh = m0 + half * 128;
        __syncthreads();
        for (int i = tid; i < 64 * 128; i += 256) {
            int r = i >> 7, c = i & 127;
            vsT[c][r] = fmaf(ascale[64 + r], qkv[((size_t)b * COUT + 80 + r) * MPIX + mh + c],
                             dshift[64 + r]);
        }
        __syncthreads();
        for (int mm = 0; mm < 128; mm++) {
            float vv = vsT[mm][vc];
#pragma unroll
            for (int i = 0; i < 4; i++) {
                int kc = kg * 4 + i;
                acc[i] = fmaf(p[((size_t)b * 16 + kc) * MPIX + mh + mm], vv, acc[i]);
            }
        }
    }
#pragma unroll
    for (int i = 0; i < 4; i++) {
        int kc = kg * 4 + i;
        clpart[(((size_t)b * 16 + mc) * 16 + kc) * 64 + vc] = acc[i];
    }
}

__global__ void cl_reduce(const float* __restrict__ clpart, float* __restrict__ cl) {
    int b = blockIdx.x;
    for (int o = threadIdx.x; o < 1024; o += 256) {
        float s = 0.f;
        for (int mc = 0; mc < 16; mc++)
            s += clpart[((size_t)b * 16 + mc) * 1024 + o];
        cl[(size_t)b * 1024 + o] = s;
    }
}

// ---------------- K6: BN q + pack bf16 pairs, in place ----------------
__global__ void __launch_bounds__(256) bnq_t(float* __restrict__ qkv,
                                             const float* __restrict__ ascale,
                                             const float* __restrict__ dshift) {
    __shared__ float sv[64][65];   // [m][c]
    int mt = blockIdx.x, b = blockIdx.y;
    int m0 = mt * 64;
    float* qb = qkv + (size_t)b * COUT * MPIX;
    int tid = threadIdx.x;
    int c = tid & 63, mg = tid >> 6;
    float a = ascale[c], d = dshift[c];
#pragma unroll
    for (int i = 0; i < 16; i++) {
        int m = mg * 16 + i;
        sv[m][c] = fmaf(a, qb[(size_t)(m0 + m) * 64 + c], d);
    }
    __syncthreads();
    int m = tid >> 2, jb = (tid & 3) * 8;   // 8 dwords = 16 channels per thread
    unsigned dw[8];
#pragma unroll
    for (int j = 0; j < 8; j++) {
        int cc = jb * 2 + 2 * j;
        dw[j] = (unsigned)f2bf(sv[m][cc]) | ((unsigned)f2bf(sv[m][cc + 1]) << 16);
    }
    unsigned* dst = (unsigned*)qb + (size_t)(m0 + m) * 64 + jb;
    *(uint4*)dst = make_uint4(dw[0], dw[1], dw[2], dw[3]);
    *(uint4*)(dst + 4) = make_uint4(dw[4], dw[5], dw[6], dw[7]);
}

// ---------------- K8: fused MFMA conv + lambda epilogue (R16-best) ----------------
// z-split (54-row half-image, 19KB LDS, grid 2048), ring-4 weights, bounds(256,4).
#define SPW 88
#define LD_FRAG(P) __builtin_bit_cast(s16x8, make_int4((P)[0], (P)[2], (P)[4], (P)[6]))
#define STEP(DY, J) do {                                                        \
    const unsigned* pnew_ = xbase + ((DY) + 3) * SPW;                           \
    rw[((J) + 3) & 3][0] = LD_FRAG(pnew_);                                      \
    rw[((J) + 3) & 3][1] = LD_FRAG(pnew_ + 16);                                 \
    int dyn_ = ((DY) + 3 < 22) ? (DY) + 3 : 22;                                 \
    wr[((J) + 3) & 3] = wf[dyn_ * 64 + lane];                                   \
    _Pragma("unroll")                                                           \
    for (int ty_ = 0; ty_ < 4; ty_++) {                                         \
      _Pragma("unroll")                                                         \
      for (int x2_ = 0; x2_ < 2; x2_++) {                                       \
        int t_ = ty_ * 2 + x2_;                                                 \
        acc[t_] = __builtin_amdgcn_mfma_f32_16x16x32_bf16(                      \
            wr[(J) & 3], rw[((J) + ty_) & 3][x2_], acc[t_], 0, 0, 0);           \
      }                                                                         \
    }                                                                           \
  } while (0)

__global__ void __launch_bounds__(256, 4) lambda_main(
    const float* __restrict__ qkv, const float* __restrict__ ascale,
    const float* __restrict__ dshift, const float* __restrict__ cl,
    const short* __restrict__ wfrag, const float* __restrict__ bl,
    float* __restrict__ out) {
    __shared__ unsigned spack[54 * SPW + 8];
    __shared__ float sck[16];

    int vc = blockIdx.x, b = blockIdx.y, h = blockIdx.z;
    int tid = threadIdx.x;

    if (tid < 16) sck[tid] = cl[((size_t)b * 16 + tid) * 64 + vc] + bl[tid];

    float av = ascale[64 + vc], dv = dshift[64 + vc];
    const float* vrow = qkv + ((size_t)b * COUT + 80 + vc) * MPIX;
    for (int i = tid; i < 54 * SPW; i += 256) {
        int y = i / SPW, e = i - y * SPW;
        int iy = h * 32 + y - PADH;
        float f0 = 0.f, f1 = 0.f;
        if ((unsigned)iy < 64u) {
            int ix0 = e - PADH, ix1 = e - PADH + 1;
            if ((unsigned)ix0 < 64u) f0 = fmaf(av, vrow[iy * 64 + ix0], dv);
            if ((unsigned)ix1 < 64u) f1 = fmaf(av, vrow[iy * 64 + ix1], dv);
        }
        spack[i] = (unsigned)f2bf(f0) | ((unsigned)f2bf(f1) << 16);
    }
    if (tid < 8) spack[54 * SPW + tid] = 0u;
    __syncthreads();

    int lane = tid & 63;
    int wv = tid >> 6;
    int px = lane & 15;
    int kg = lane >> 4;
    const s16x8* wf = (const s16x8*)wfrag;

    const unsigned* qtb = (const unsigned*)(qkv + (size_t)b * COUT * MPIX);  // bf16-packed q
    float* ob = out + (size_t)b * 256 * MPIX;

    float sck_l[4];
#pragma unroll
    for (int r = 0; r < 4; r++) sck_l[r] = sck[kg * 4 + r];

#pragma unroll 1
    for (int gg = 0; gg < 2; gg++) {
        int y0 = (gg * 4 + wv) * 4;            // local row base within this half
        const unsigned* base = &spack[y0 * SPW + px + kg * 8];

#pragma unroll 1
        for (int xh = 0; xh < 2; xh++) {
            const unsigned* xbase = base + xh * 32;
            f32x4 acc[8];
#pragma unroll
            for (int t = 0; t < 8; t++) acc[t] = 0.f;

            s16x8 rw[4][2];   // sliding 4-row window, slot = row & 3
            s16x8 wr[4];      // ring-4 weight prefetch (weights are L1-resident)
#pragma unroll
            for (int r0 = 0; r0 < 3; r0++) {
                const unsigned* p = xbase + r0 * SPW;
                rw[r0][0] = LD_FRAG(p);
                rw[r0][1] = LD_FRAG(p + 16);
            }
#pragma unroll
            for (int s = 0; s < 3; s++) wr[s] = wf[s * 64 + lane];

#pragma unroll 1
            for (int i8 = 0; i8 < 2; i8++) {
                int dyb = i8 * 8;
                STEP(dyb + 0, 0);
                STEP(dyb + 1, 1);
                STEP(dyb + 2, 2);
                STEP(dyb + 3, 3);
                STEP(dyb + 4, 4);
                STEP(dyb + 5, 5);
                STEP(dyb + 6, 6);
                STEP(dyb + 7, 7);
            }
            STEP(16, 0);
            STEP(17, 1);
            STEP(18, 2);
            STEP(19, 3);
            STEP(20, 4);
            STEP(21, 5);
            STEP(22, 6);

#pragma unroll
            for (int t = 0; t < 8; t++) {
                int ty = t >> 1, x2 = t & 1;
                int m0 = (h * 32 + y0 + ty) * 64 + (xh * 2 + x2) * 16;
                float lam[4];
#pragma unroll
                for (int r = 0; r < 4; r++) lam[r] = acc[t][r] + sck_l[r];
                const unsigned* qp = &qtb[(size_t)(m0 + px) * 64 + kg * 8];
                uint4 qa = *(const uint4*)qp;
                uint4 qb4 = *(const uint4*)(qp + 4);
                unsigned dws[8] = {qa.x, qa.y, qa.z, qa.w, qb4.x, qb4.y, qb4.z, qb4.w};
                float po[4] = {0.f, 0.f, 0.f, 0.f};
#pragma unroll
                for (int d = 0; d < 8; d++) {
                    float q0 = __builtin_bit_cast(float, dws[d] << 16);
                    float q1 = __builtin_bit_cast(float, dws[d] & 0xffff0000u);
                    int i0 = 2 * d, i1 = 2 * d + 1;
                    po[i0 & 3] = fmaf(q0, lam[i0 >> 2], po[i0 & 3]);
                    po[i1 & 3] = fmaf(q1, lam[i1 >> 2], po[i1 & 3]);
                }
#pragma unroll
                for (int n = 0; n < 4; n++) {
                    po[n] += __shfl_xor(po[n], 16);
                    po[n] += __shfl_xor(po[n], 32);
                }
                float sv = (kg == 0) ? po[0] : (kg == 1) ? po[1] : (kg == 2) ? po[2] : po[3];
                ob[(size_t)(kg * 64 + vc) * MPIX + m0 + px] = sv;
            }
        }
    }
}

// ---------------- launch ----------------
extern "C" void kernel_launch(void* const* d_in, const int* in_sizes, int n_in,
                              void* d_out, int out_size, void* d_ws, size_t ws_size,
                              hipStream_t stream) {
    const float* x      = (const float*)d_in[0];
    const float* w_qkv  = (const float*)d_in[1];
    const float* gq     = (const float*)d_in[2];
    const float* bq     = (const float*)d_in[3];
    const float* gv     = (const float*)d_in[4];
    const float* bv     = (const float*)d_in[5];
    const float* wl     = (const float*)d_in[6];
    const float* bl     = (const float*)d_in[7];
    float* out = (float*)d_out;

    float* ws     = (float*)d_ws;
    float* qkv    = ws;                    // 16*144*4096 = 9,437,184 (q region holds [m][64c])
    float* p      = qkv + 9437184;         // 1,048,576
    float* ascale = p + 1048576;           // 128
    float* dshift = ascale + 128;          // 128
    float* clpart = dshift + 128;          // 262,144
    float* clb    = clpart + 262144;       // 16,384
    short* wfrag  = (short*)(clb + 16384); // 11,776 halfs
    short* wqf    = (short*)(clb + 16384 + 5888 + 64);  // 36,864 halfs
    float* statpart = (float*)(wqf + 36864);            // 144*16*64*2 = 294,912 floats

    prep_frags<<<190, 256, 0, stream>>>(w_qkv, wl, wqf, wfrag);
    gemm_qkv<<<dim3(64, 16), 256, 0, stream>>>(x, wqf, qkv, statpart);
    stats_finalize<<<128, 256, 0, stream>>>(statpart, gq, bq, gv, bv, ascale, dshift);
    softmax_k<<<256, 256, 0, stream>>>(qkv, p);
    cl_partial<<<dim3(16, 16), 256, 0, stream>>>(qkv, p, ascale, dshift, clpart);
    cl_reduce<<<16, 256, 0, stream>>>(clpart, clb);
    bnq_t<<<dim3(64, 16), 256, 0, stream>>>(qkv, ascale, dshift);
    lambda_main<<<dim3(64, 16, 2), 256, 0, stream>>>(qkv, ascale, dshift, clb, wfrag, bl, out);
}

// Round 18
// 200.583 us; speedup vs baseline: 1.0991x; 1.0075x over previous
//
#include <hip/hip_runtime.h>
#include <math.h>

#define NB    16      // batch
#define CDIM  256
#define COUT  144     // 64 q + 16 k + 64 v
#define MPIX  4096    // 64*64
#define SCOPE 23
#define PADH  11
#define BNEPS 1e-5f

typedef __attribute__((ext_vector_type(4))) float f32x4;
typedef __attribute__((ext_vector_type(8))) short s16x8;

__device__ __forceinline__ unsigned short f2bf(float f) {
    unsigned u = __builtin_bit_cast(unsigned, f);
    unsigned r = (u + 0x7FFFu + ((u >> 16) & 1u)) >> 16;
    return (unsigned short)r;
}

// ---------------- K0: both weight-fragment preps merged ----------------
__global__ void prep_frags(const float* __restrict__ w, const float* __restrict__ wl,
                           short* __restrict__ wqf, short* __restrict__ wfrag) {
    int i = blockIdx.x * 256 + threadIdx.x;
    if (i < 36864) {
        int j = i & 7, lane = (i >> 3) & 63;
        int fi = i >> 9;
        int mf = fi % 9, kc = fi / 9;
        int o = mf * 16 + (lane & 15);
        int c = kc * 32 + (lane >> 4) * 8 + j;
        wqf[i] = (short)f2bf(w[o * 256 + c]);
        return;
    }
    int i2 = i - 36864;
    if (i2 < 23 * 64 * 8) {
        int j = i2 & 7, l = (i2 >> 3) & 63, dy = i2 >> 9;
        int k = l & 15, t = ((l >> 4) << 3) + j;
        float wv = (t < SCOPE) ? wl[k * 529 + dy * 23 + t] : 0.f;
        wfrag[i2] = (short)f2bf(wv);
    }
}

// ---------------- K1: qkv GEMM + fused BN stat partials + fused softmax-denominator --
// q channels TRANSPOSED [m][64c] f32; k,v linear. statpart[ch][b][mt] = (sum,sumsq).
// kpart[(kc*16+b)*64+mt] = per-block sum of exp(k) (shift-free softmax denominator).
__global__ void __launch_bounds__(256, 4) gemm_qkv(const float* __restrict__ x,
                                                   const short* __restrict__ wqf,
                                                   float* __restrict__ qkv,
                                                   float* __restrict__ statpart,
                                                   float* __restrict__ kpart) {
    __shared__ unsigned pk[16 * 65];
    __shared__ float ssum[4][144], ssq[4][144];
    __shared__ float sse[4][16];
    int mt = blockIdx.x, b = blockIdx.y;
    int m0 = mt * 64;
    int tid = threadIdx.x;
    int px64 = tid & 63, c2b = tid >> 6;
    int lane = tid & 63, wv = tid >> 6;
    int pxl = lane & 15, kgq = lane >> 4;
    const float* xb = x + (size_t)b * CDIM * MPIX;
    float* qtb = qkv + (size_t)b * COUT * MPIX;   // q region, [m][64] layout
    const s16x8* wfv = (const s16x8*)wqf;

    f32x4 acc[9];
#pragma unroll
    for (int mf = 0; mf < 9; mf++) acc[mf] = 0.f;

#pragma unroll 1
    for (int kc = 0; kc < 8; kc++) {
        if (kc > 0) __syncthreads();
#pragma unroll
        for (int it = 0; it < 4; it++) {
            int c2 = c2b + it * 4;
            float x0 = xb[(size_t)(kc * 32 + 2 * c2) * MPIX + m0 + px64];
            float x1 = xb[(size_t)(kc * 32 + 2 * c2 + 1) * MPIX + m0 + px64];
            pk[c2 * 65 + px64] = (unsigned)f2bf(x0) | ((unsigned)f2bf(x1) << 16);
        }
        __syncthreads();
        const unsigned* bp = &pk[kgq * 4 * 65 + wv * 16 + pxl];
        int4 bi = make_int4(bp[0], bp[65], bp[130], bp[195]);
        s16x8 bf = __builtin_bit_cast(s16x8, bi);
#pragma unroll
        for (int mf = 0; mf < 9; mf++) {
            s16x8 af = wfv[(kc * 9 + mf) * 64 + lane];
            acc[mf] = __builtin_amdgcn_mfma_f32_16x16x32_bf16(af, bf, acc[mf], 0, 0, 0);
        }
    }

    int m = m0 + wv * 16 + pxl;
#pragma unroll
    for (int mf = 0; mf < 9; mf++) {
#pragma unroll
        for (int r = 0; r < 4; r++) {
            int o = mf * 16 + kgq * 4 + r;
            if (mf < 4) qtb[(size_t)m * 64 + o] = acc[mf][r];                  // q transposed
            else qkv[((size_t)b * COUT + o) * MPIX + m] = acc[mf][r];          // k,v linear
        }
    }

    // fused stats: reduce over 16 px-lanes of each kgq group, then over 4 waves.
    // k channels (mf==4) additionally accumulate exp-sum (softmax denominator, C=0).
#pragma unroll
    for (int mf = 0; mf < 9; mf++) {
#pragma unroll
        for (int r = 0; r < 4; r++) {
            float s = acc[mf][r];
            float s2 = s * s;
#pragma unroll
            for (int off = 1; off < 16; off <<= 1) {
                s += __shfl_xor(s, off);
                s2 += __shfl_xor(s2, off);
            }
            if (mf == 4) {
                float e = __expf(acc[mf][r]);
#pragma unroll
                for (int off = 1; off < 16; off <<= 1) e += __shfl_xor(e, off);
                if (pxl == 0) sse[wv][kgq * 4 + r] = e;
            }
            if (pxl == 0) {
                int ch = mf * 16 + kgq * 4 + r;
                ssum[wv][ch] = s;
                ssq[wv][ch] = s2;
            }
        }
    }
    __syncthreads();
    if (tid < 144) {
        float s = ssum[0][tid] + ssum[1][tid] + ssum[2][tid] + ssum[3][tid];
        float s2 = ssq[0][tid] + ssq[1][tid] + ssq[2][tid] + ssq[3][tid];
        size_t idx = (((size_t)tid * 16 + b) * 64 + mt) * 2;
        statpart[idx + 0] = s;
        statpart[idx + 1] = s2;
    }
    if (tid >= 144 && tid < 160) {
        int kc = tid - 144;
        float e = sse[0][kc] + sse[1][kc] + sse[2][kc] + sse[3][kc];
        kpart[((size_t)kc * 16 + b) * 64 + mt] = e;
    }
}

// ---------------- K3: finalize — blocks 0..127 BN scale/shift; 128..383 softmax rinv --
__global__ void stats_finalize(const float* __restrict__ statpart,
                               const float* __restrict__ kpart,
                               const float* __restrict__ gq, const float* __restrict__ bq,
                               const float* __restrict__ gv, const float* __restrict__ bv,
                               float* __restrict__ ascale, float* __restrict__ dshift,
                               float* __restrict__ ksm) {
    int tid = threadIdx.x;
    if (blockIdx.x >= 128) {
        int id = blockIdx.x - 128;                // = kc*16 + b
        if (tid < 64) {
            float s = kpart[(size_t)id * 64 + tid];
#pragma unroll
            for (int off = 32; off > 0; off >>= 1) s += __shfl_down(s, off);
            if (tid == 0) ksm[id] = 1.0f / s;
        }
        return;
    }
    int sch = blockIdx.x;                         // 0..127 stat channel
    int gch = (sch < 64) ? sch : sch + 16;        // gemm channel (skip k 64..79)
    const float* sp = statpart + (size_t)gch * 1024 * 2;
    float s = 0.f, s2 = 0.f;
    for (int i = tid; i < 1024; i += 256) {
        s += sp[i * 2 + 0];
        s2 += sp[i * 2 + 1];
    }
#pragma unroll
    for (int off = 32; off > 0; off >>= 1) {
        s += __shfl_down(s, off);
        s2 += __shfl_down(s2, off);
    }
    __shared__ float red[8];
    int wid = tid >> 6, lane = tid & 63;
    if (lane == 0) { red[wid * 2] = s; red[wid * 2 + 1] = s2; }
    __syncthreads();
    if (tid == 0) {
        float ts = 0.f, ts2 = 0.f;
#pragma unroll
        for (int w2 = 0; w2 < 4; w2++) { ts += red[w2 * 2]; ts2 += red[w2 * 2 + 1]; }
        const float invN = 1.0f / 65536.0f;
        float mean = ts * invN;
        float var = ts2 * invN - mean * mean;
        float g = (sch < 64) ? gq[sch] : gv[sch - 64];
        float be = (sch < 64) ? bq[sch] : bv[sch - 64];
        float a = g * rsqrtf(var + BNEPS);
        ascale[sch] = a;
        dshift[sch] = be - mean * a;
    }
}

// ---------------- K5: content lambda partials (softmax computed inline) ----------------
__global__ void cl_partial(const float* __restrict__ qkv, const float* __restrict__ ksm,
                           const float* __restrict__ ascale, const float* __restrict__ dshift,
                           float* __restrict__ clpart) {
    __shared__ float vsT[128][65];
    __shared__ float pk2[16][132];
    __shared__ float skr[16];
    int mc = blockIdx.x, b = blockIdx.y;
    int m0 = mc * 256;
    int tid = threadIdx.x;
    int vc = tid & 63, kg = tid >> 6;
    if (tid < 16) skr[tid] = ksm[(size_t)tid * 16 + b];
    float acc[4] = {0.f, 0.f, 0.f, 0.f};
    for (int half = 0; half < 2; half++) {
        int mh = m0 + half * 128;
        __syncthreads();
        for (int i = tid; i < 64 * 128; i += 256) {
            int r = i >> 7, c = i & 127;
            vsT[c][r] = fmaf(ascale[64 + r], qkv[((size_t)b * COUT + 80 + r) * MPIX + mh + c],
                             dshift[64 + r]);
        }
        for (int i = tid; i < 16 * 128; i += 256) {
            int kc = i >> 7, mm = i & 127;
            pk2[kc][mm] = __expf(qkv[((size_t)b * COUT + 64 + kc) * MPIX + mh + mm]) * skr[kc];
        }
        __syncthreads();
        for (int mm = 0; mm < 128; mm++) {
            float vv = vsT[mm][vc];
#pragma unroll
            for (int i = 0; i < 4; i++) {
                int kc = kg * 4 + i;
                acc[i] = fmaf(pk2[kc][mm], vv, acc[i]);
            }
        }
    }
#pragma unroll
    for (int i = 0; i < 4; i++) {
        int kc = kg * 4 + i;
        clpart[(((size_t)b * 16 + mc) * 16 + kc) * 64 + vc] = acc[i];
    }
}

__global__ void cl_reduce(const float* __restrict__ clpart, float* __restrict__ cl) {
    int b = blockIdx.x;
    for (int o = threadIdx.x; o < 1024; o += 256) {
        float s = 0.f;
        for (int mc = 0; mc < 16; mc++)
            s += clpart[((size_t)b * 16 + mc) * 1024 + o];
        cl[(size_t)b * 1024 + o] = s;
    }
}

// ---------------- K6: BN q + pack bf16 pairs, in place ----------------
__global__ void __launch_bounds__(256) bnq_t(float* __restrict__ qkv,
                                             const float* __restrict__ ascale,
                                             const float* __restrict__ dshift) {
    __shared__ float sv[64][65];   // [m][c]
    int mt = blockIdx.x, b = blockIdx.y;
    int m0 = mt * 64;
    float* qb = qkv + (size_t)b * COUT * MPIX;
    int tid = threadIdx.x;
    int c = tid & 63, mg = tid >> 6;
    float a = ascale[c], d = dshift[c];
#pragma unroll
    for (int i = 0; i < 16; i++) {
        int m = mg * 16 + i;
        sv[m][c] = fmaf(a, qb[(size_t)(m0 + m) * 64 + c], d);
    }
    __syncthreads();
    int m = tid >> 2, jb = (tid & 3) * 8;   // 8 dwords = 16 channels per thread
    unsigned dw[8];
#pragma unroll
    for (int j = 0; j < 8; j++) {
        int cc = jb * 2 + 2 * j;
        dw[j] = (unsigned)f2bf(sv[m][cc]) | ((unsigned)f2bf(sv[m][cc + 1]) << 16);
    }
    unsigned* dst = (unsigned*)qb + (size_t)(m0 + m) * 64 + jb;
    *(uint4*)dst = make_uint4(dw[0], dw[1], dw[2], dw[3]);
    *(uint4*)(dst + 4) = make_uint4(dw[4], dw[5], dw[6], dw[7]);
}

// ---------------- K8: fused MFMA conv + lambda epilogue (R16-best) ----------------
// z-split (54-row half-image, 19KB LDS, grid 2048), ring-4 weights, bounds(256,4).
#define SPW 88
#define LD_FRAG(P) __builtin_bit_cast(s16x8, make_int4((P)[0], (P)[2], (P)[4], (P)[6]))
#define STEP(DY, J) do {                                                        \
    const unsigned* pnew_ = xbase + ((DY) + 3) * SPW;                           \
    rw[((J) + 3) & 3][0] = LD_FRAG(pnew_);                                      \
    rw[((J) + 3) & 3][1] = LD_FRAG(pnew_ + 16);                                 \
    int dyn_ = ((DY) + 3 < 22) ? (DY) + 3 : 22;                                 \
    wr[((J) + 3) & 3] = wf[dyn_ * 64 + lane];                                   \
    _Pragma("unroll")                                                           \
    for (int ty_ = 0; ty_ < 4; ty_++) {                                         \
      _Pragma("unroll")                                                         \
      for (int x2_ = 0; x2_ < 2; x2_++) {                                       \
        int t_ = ty_ * 2 + x2_;                                                 \
        acc[t_] = __builtin_amdgcn_mfma_f32_16x16x32_bf16(                      \
            wr[(J) & 3], rw[((J) + ty_) & 3][x2_], acc[t_], 0, 0, 0);           \
      }                                                                         \
    }                                                                           \
  } while (0)

__global__ void __launch_bounds__(256, 4) lambda_main(
    const float* __restrict__ qkv, const float* __restrict__ ascale,
    const float* __restrict__ dshift, const float* __restrict__ cl,
    const short* __restrict__ wfrag, const float* __restrict__ bl,
    float* __restrict__ out) {
    __shared__ unsigned spack[54 * SPW + 8];
    __shared__ float sck[16];

    int vc = blockIdx.x, b = blockIdx.y, h = blockIdx.z;
    int tid = threadIdx.x;

    if (tid < 16) sck[tid] = cl[((size_t)b * 16 + tid) * 64 + vc] + bl[tid];

    float av = ascale[64 + vc], dv = dshift[64 + vc];
    const float* vrow = qkv + ((size_t)b * COUT + 80 + vc) * MPIX;
    for (int i = tid; i < 54 * SPW; i += 256) {
        int y = i / SPW, e = i - y * SPW;
        int iy = h * 32 + y - PADH;
        float f0 = 0.f, f1 = 0.f;
        if ((unsigned)iy < 64u) {
            int ix0 = e - PADH, ix1 = e - PADH + 1;
            if ((unsigned)ix0 < 64u) f0 = fmaf(av, vrow[iy * 64 + ix0], dv);
            if ((unsigned)ix1 < 64u) f1 = fmaf(av, vrow[iy * 64 + ix1], dv);
        }
        spack[i] = (unsigned)f2bf(f0) | ((unsigned)f2bf(f1) << 16);
    }
    if (tid < 8) spack[54 * SPW + tid] = 0u;
    __syncthreads();

    int lane = tid & 63;
    int wv = tid >> 6;
    int px = lane & 15;
    int kg = lane >> 4;
    const s16x8* wf = (const s16x8*)wfrag;

    const unsigned* qtb = (const unsigned*)(qkv + (size_t)b * COUT * MPIX);  // bf16-packed q
    float* ob = out + (size_t)b * 256 * MPIX;

    float sck_l[4];
#pragma unroll
    for (int r = 0; r < 4; r++) sck_l[r] = sck[kg * 4 + r];

#pragma unroll 1
    for (int gg = 0; gg < 2; gg++) {
        int y0 = (gg * 4 + wv) * 4;            // local row base within this half
        const unsigned* base = &spack[y0 * SPW + px + kg * 8];

#pragma unroll 1
        for (int xh = 0; xh < 2; xh++) {
            const unsigned* xbase = base + xh * 32;
            f32x4 acc[8];
#pragma unroll
            for (int t = 0; t < 8; t++) acc[t] = 0.f;

            s16x8 rw[4][2];   // sliding 4-row window, slot = row & 3
            s16x8 wr[4];      // ring-4 weight prefetch (weights are L1-resident)
#pragma unroll
            for (int r0 = 0; r0 < 3; r0++) {
                const unsigned* p = xbase + r0 * SPW;
                rw[r0][0] = LD_FRAG(p);
                rw[r0][1] = LD_FRAG(p + 16);
            }
#pragma unroll
            for (int s = 0; s < 3; s++) wr[s] = wf[s * 64 + lane];

#pragma unroll 1
            for (int i8 = 0; i8 < 2; i8++) {
                int dyb = i8 * 8;
                STEP(dyb + 0, 0);
                STEP(dyb + 1, 1);
                STEP(dyb + 2, 2);
                STEP(dyb + 3, 3);
                STEP(dyb + 4, 4);
                STEP(dyb + 5, 5);
                STEP(dyb + 6, 6);
                STEP(dyb + 7, 7);
            }
            STEP(16, 0);
            STEP(17, 1);
            STEP(18, 2);
            STEP(19, 3);
            STEP(20, 4);
            STEP(21, 5);
            STEP(22, 6);

#pragma unroll
            for (int t = 0; t < 8; t++) {
                int ty = t >> 1, x2 = t & 1;
                int m0 = (h * 32 + y0 + ty) * 64 + (xh * 2 + x2) * 16;
                float lam[4];
#pragma unroll
                for (int r = 0; r < 4; r++) lam[r] = acc[t][r] + sck_l[r];
                const unsigned* qp = &qtb[(size_t)(m0 + px) * 64 + kg * 8];
                uint4 qa = *(const uint4*)qp;
                uint4 qb4 = *(const uint4*)(qp + 4);
                unsigned dws[8] = {qa.x, qa.y, qa.z, qa.w, qb4.x, qb4.y, qb4.z, qb4.w};
                float po[4] = {0.f, 0.f, 0.f, 0.f};
#pragma unroll
                for (int d = 0; d < 8; d++) {
                    float q0 = __builtin_bit_cast(float, dws[d] << 16);
                    float q1 = __builtin_bit_cast(float, dws[d] & 0xffff0000u);
                    int i0 = 2 * d, i1 = 2 * d + 1;
                    po[i0 & 3] = fmaf(q0, lam[i0 >> 2], po[i0 & 3]);
                    po[i1 & 3] = fmaf(q1, lam[i1 >> 2], po[i1 & 3]);
                }
#pragma unroll
                for (int n = 0; n < 4; n++) {
                    po[n] += __shfl_xor(po[n], 16);
                    po[n] += __shfl_xor(po[n], 32);
                }
                float sv = (kg == 0) ? po[0] : (kg == 1) ? po[1] : (kg == 2) ? po[2] : po[3];
                ob[(size_t)(kg * 64 + vc) * MPIX + m0 + px] = sv;
            }
        }
    }
}

// ---------------- launch ----------------
extern "C" void kernel_launch(void* const* d_in, const int* in_sizes, int n_in,
                              void* d_out, int out_size, void* d_ws, size_t ws_size,
                              hipStream_t stream) {
    const float* x      = (const float*)d_in[0];
    const float* w_qkv  = (const float*)d_in[1];
    const float* gq     = (const float*)d_in[2];
    const float* bq     = (const float*)d_in[3];
    const float* gv     = (const float*)d_in[4];
    const float* bv     = (const float*)d_in[5];
    const float* wl     = (const float*)d_in[6];
    const float* bl     = (const float*)d_in[7];
    float* out = (float*)d_out;

    float* ws     = (float*)d_ws;
    float* qkv    = ws;                    // 9,437,184 floats (q region holds [m][64c])
    float* ascale = qkv + 9437184;         // 128
    float* dshift = ascale + 128;          // 128
    float* clpart = dshift + 128;          // 262,144
    float* clb    = clpart + 262144;       // 16,384
    short* wfrag  = (short*)(clb + 16384); // 11,776 halfs
    short* wqf    = (short*)(clb + 16384 + 5888 + 64);  // 36,864 halfs
    float* statpart = (float*)(wqf + 36864);            // 294,912 floats
    float* kpart  = statpart + 294912;     // 16,384
    float* ksm    = kpart + 16384;         // 256

    prep_frags<<<190, 256, 0, stream>>>(w_qkv, wl, wqf, wfrag);
    gemm_qkv<<<dim3(64, 16), 256, 0, stream>>>(x, wqf, qkv, statpart, kpart);
    stats_finalize<<<384, 256, 0, stream>>>(statpart, kpart, gq, bq, gv, bv,
                                            ascale, dshift, ksm);
    cl_partial<<<dim3(16, 16), 256, 0, stream>>>(qkv, ksm, ascale, dshift, clpart);
    cl_reduce<<<16, 256, 0, stream>>>(clpart, clb);
    bnq_t<<<dim3(64, 16), 256, 0, stream>>>(qkv, ascale, dshift);
    lambda_main<<<dim3(64, 16, 2), 256, 0, stream>>>(qkv, ascale, dshift, clb, wfrag, bl, out);
}

// Round 19
// 192.950 us; speedup vs baseline: 1.1426x; 1.0396x over previous
//
#include <hip/hip_runtime.h>
#include <math.h>

#define NB    16      // batch
#define CDIM  256
#define COUT  144     // 64 q + 16 k + 64 v
#define MPIX  4096    // 64*64
#define SCOPE 23
#define PADH  11
#define BNEPS 1e-5f

typedef __attribute__((ext_vector_type(4))) float f32x4;
typedef __attribute__((ext_vector_type(8))) short s16x8;

__device__ __forceinline__ unsigned short f2bf(float f) {
    unsigned u = __builtin_bit_cast(unsigned, f);
    unsigned r = (u + 0x7FFFu + ((u >> 16) & 1u)) >> 16;
    return (unsigned short)r;
}

// ---------------- K0: both weight-fragment preps merged ----------------
__global__ void prep_frags(const float* __restrict__ w, const float* __restrict__ wl,
                           short* __restrict__ wqf, short* __restrict__ wfrag) {
    int i = blockIdx.x * 256 + threadIdx.x;
    if (i < 36864) {
        int j = i & 7, lane = (i >> 3) & 63;
        int fi = i >> 9;
        int mf = fi % 9, kc = fi / 9;
        int o = mf * 16 + (lane & 15);
        int c = kc * 32 + (lane >> 4) * 8 + j;
        wqf[i] = (short)f2bf(w[o * 256 + c]);
        return;
    }
    int i2 = i - 36864;
    if (i2 < 23 * 64 * 8) {
        int j = i2 & 7, l = (i2 >> 3) & 63, dy = i2 >> 9;
        int k = l & 15, t = ((l >> 4) << 3) + j;
        float wv = (t < SCOPE) ? wl[k * 529 + dy * 23 + t] : 0.f;
        wfrag[i2] = (short)f2bf(wv);
    }
}

// ---------------- K1: qkv GEMM + fused BN stat partials + softmax denominator ----
__global__ void __launch_bounds__(256, 4) gemm_qkv(const float* __restrict__ x,
                                                   const short* __restrict__ wqf,
                                                   float* __restrict__ qkv,
                                                   float* __restrict__ statpart,
                                                   float* __restrict__ kpart) {
    __shared__ unsigned pk[16 * 65];
    __shared__ float ssum[4][144], ssq[4][144];
    __shared__ float sse[4][16];
    int mt = blockIdx.x, b = blockIdx.y;
    int m0 = mt * 64;
    int tid = threadIdx.x;
    int px64 = tid & 63, c2b = tid >> 6;
    int lane = tid & 63, wv = tid >> 6;
    int pxl = lane & 15, kgq = lane >> 4;
    const float* xb = x + (size_t)b * CDIM * MPIX;
    float* qtb = qkv + (size_t)b * COUT * MPIX;
    const s16x8* wfv = (const s16x8*)wqf;

    f32x4 acc[9];
#pragma unroll
    for (int mf = 0; mf < 9; mf++) acc[mf] = 0.f;

#pragma unroll 1
    for (int kc = 0; kc < 8; kc++) {
        if (kc > 0) __syncthreads();
#pragma unroll
        for (int it = 0; it < 4; it++) {
            int c2 = c2b + it * 4;
            float x0 = xb[(size_t)(kc * 32 + 2 * c2) * MPIX + m0 + px64];
            float x1 = xb[(size_t)(kc * 32 + 2 * c2 + 1) * MPIX + m0 + px64];
            pk[c2 * 65 + px64] = (unsigned)f2bf(x0) | ((unsigned)f2bf(x1) << 16);
        }
        __syncthreads();
        const unsigned* bp = &pk[kgq * 4 * 65 + wv * 16 + pxl];
        int4 bi = make_int4(bp[0], bp[65], bp[130], bp[195]);
        s16x8 bf = __builtin_bit_cast(s16x8, bi);
#pragma unroll
        for (int mf = 0; mf < 9; mf++) {
            s16x8 af = wfv[(kc * 9 + mf) * 64 + lane];
            acc[mf] = __builtin_amdgcn_mfma_f32_16x16x32_bf16(af, bf, acc[mf], 0, 0, 0);
        }
    }

    int m = m0 + wv * 16 + pxl;
#pragma unroll
    for (int mf = 0; mf < 9; mf++) {
#pragma unroll
        for (int r = 0; r < 4; r++) {
            int o = mf * 16 + kgq * 4 + r;
            if (mf < 4) qtb[(size_t)m * 64 + o] = acc[mf][r];
            else qkv[((size_t)b * COUT + o) * MPIX + m] = acc[mf][r];
        }
    }

#pragma unroll
    for (int mf = 0; mf < 9; mf++) {
#pragma unroll
        for (int r = 0; r < 4; r++) {
            float s = acc[mf][r];
            float s2 = s * s;
#pragma unroll
            for (int off = 1; off < 16; off <<= 1) {
                s += __shfl_xor(s, off);
                s2 += __shfl_xor(s2, off);
            }
            if (mf == 4) {
                float e = __expf(acc[mf][r]);
#pragma unroll
                for (int off = 1; off < 16; off <<= 1) e += __shfl_xor(e, off);
                if (pxl == 0) sse[wv][kgq * 4 + r] = e;
            }
            if (pxl == 0) {
                int ch = mf * 16 + kgq * 4 + r;
                ssum[wv][ch] = s;
                ssq[wv][ch] = s2;
            }
        }
    }
    __syncthreads();
    if (tid < 144) {
        float s = ssum[0][tid] + ssum[1][tid] + ssum[2][tid] + ssum[3][tid];
        float s2 = ssq[0][tid] + ssq[1][tid] + ssq[2][tid] + ssq[3][tid];
        size_t idx = (((size_t)tid * 16 + b) * 64 + mt) * 2;
        statpart[idx + 0] = s;
        statpart[idx + 1] = s2;
    }
    if (tid >= 144 && tid < 160) {
        int kc = tid - 144;
        float e = sse[0][kc] + sse[1][kc] + sse[2][kc] + sse[3][kc];
        kpart[((size_t)kc * 16 + b) * 64 + mt] = e;
    }
}

// ---------------- K3: finalize — blocks 0..127 BN; 128..383 softmax rinv ----------
__global__ void stats_finalize(const float* __restrict__ statpart,
                               const float* __restrict__ kpart,
                               const float* __restrict__ gq, const float* __restrict__ bq,
                               const float* __restrict__ gv, const float* __restrict__ bv,
                               float* __restrict__ ascale, float* __restrict__ dshift,
                               float* __restrict__ ksm) {
    int tid = threadIdx.x;
    if (blockIdx.x >= 128) {
        int id = blockIdx.x - 128;
        if (tid < 64) {
            float s = kpart[(size_t)id * 64 + tid];
#pragma unroll
            for (int off = 32; off > 0; off >>= 1) s += __shfl_down(s, off);
            if (tid == 0) ksm[id] = 1.0f / s;
        }
        return;
    }
    int sch = blockIdx.x;
    int gch = (sch < 64) ? sch : sch + 16;
    const float* sp = statpart + (size_t)gch * 1024 * 2;
    float s = 0.f, s2 = 0.f;
    for (int i = tid; i < 1024; i += 256) {
        s += sp[i * 2 + 0];
        s2 += sp[i * 2 + 1];
    }
#pragma unroll
    for (int off = 32; off > 0; off >>= 1) {
        s += __shfl_down(s, off);
        s2 += __shfl_down(s2, off);
    }
    __shared__ float red[8];
    int wid = tid >> 6, lane = tid & 63;
    if (lane == 0) { red[wid * 2] = s; red[wid * 2 + 1] = s2; }
    __syncthreads();
    if (tid == 0) {
        float ts = 0.f, ts2 = 0.f;
#pragma unroll
        for (int w2 = 0; w2 < 4; w2++) { ts += red[w2 * 2]; ts2 += red[w2 * 2 + 1]; }
        const float invN = 1.0f / 65536.0f;
        float mean = ts * invN;
        float var = ts2 * invN - mean * mean;
        float g = (sch < 64) ? gq[sch] : gv[sch - 64];
        float be = (sch < 64) ? bq[sch] : bv[sch - 64];
        float a = g * rsqrtf(var + BNEPS);
        ascale[sch] = a;
        dshift[sch] = be - mean * a;
    }
}

// ---------------- K5: merged cl_partial (roles 0..15) + bnq_t (roles 16..79) --------
// Both depend only on stats_finalize. Shared-LDS union.
__global__ void __launch_bounds__(256) cl_bnq(float* __restrict__ qkv,
                                              const float* __restrict__ ksm,
                                              const float* __restrict__ ascale,
                                              const float* __restrict__ dshift,
                                              float* __restrict__ clpart) {
    __shared__ float smem[128 * 65 + 16 * 132 + 16];   // 41.9 KB union
    int role = blockIdx.x, b = blockIdx.y;
    int tid = threadIdx.x;

    if (role >= 16) {
        // ---- bnq_t: BN q + pack bf16 pairs in place, rows mt*64..mt*64+63 ----
        float (*sv)[65] = (float(*)[65])smem;
        int mt = role - 16;
        int m0 = mt * 64;
        float* qb = qkv + (size_t)b * COUT * MPIX;
        int c = tid & 63, mg = tid >> 6;
        float a = ascale[c], d = dshift[c];
#pragma unroll
        for (int i = 0; i < 16; i++) {
            int m = mg * 16 + i;
            sv[m][c] = fmaf(a, qb[(size_t)(m0 + m) * 64 + c], d);
        }
        __syncthreads();
        int m = tid >> 2, jb = (tid & 3) * 8;
        unsigned dw[8];
#pragma unroll
        for (int j = 0; j < 8; j++) {
            int cc = jb * 2 + 2 * j;
            dw[j] = (unsigned)f2bf(sv[m][cc]) | ((unsigned)f2bf(sv[m][cc + 1]) << 16);
        }
        unsigned* dst = (unsigned*)qb + (size_t)(m0 + m) * 64 + jb;
        *(uint4*)dst = make_uint4(dw[0], dw[1], dw[2], dw[3]);
        *(uint4*)(dst + 4) = make_uint4(dw[4], dw[5], dw[6], dw[7]);
        return;
    }

    // ---- cl_partial with inline softmax ----
    float (*vsT)[65] = (float(*)[65])smem;                    // [128][65]
    float (*pk2)[132] = (float(*)[132])(smem + 128 * 65);     // [16][132]
    float* skr = smem + 128 * 65 + 16 * 132;                  // [16]
    int mc = role;
    int m0 = mc * 256;
    int vc = tid & 63, kg = tid >> 6;
    if (tid < 16) skr[tid] = ksm[(size_t)tid * 16 + b];
    float acc[4] = {0.f, 0.f, 0.f, 0.f};
    for (int half = 0; half < 2; half++) {
        int mh = m0 + half * 128;
        __syncthreads();
        for (int i = tid; i < 64 * 128; i += 256) {
            int r = i >> 7, c = i & 127;
            vsT[c][r] = fmaf(ascale[64 + r], qkv[((size_t)b * COUT + 80 + r) * MPIX + mh + c],
                             dshift[64 + r]);
        }
        for (int i = tid; i < 16 * 128; i += 256) {
            int kc = i >> 7, mm = i & 127;
            pk2[kc][mm] = __expf(qkv[((size_t)b * COUT + 64 + kc) * MPIX + mh + mm]) * skr[kc];
        }
        __syncthreads();
        for (int mm = 0; mm < 128; mm++) {
            float vv = vsT[mm][vc];
#pragma unroll
            for (int i = 0; i < 4; i++) {
                int kc = kg * 4 + i;
                acc[i] = fmaf(pk2[kc][mm], vv, acc[i]);
            }
        }
    }
#pragma unroll
    for (int i = 0; i < 4; i++) {
        int kc = kg * 4 + i;
        clpart[(((size_t)b * 16 + mc) * 16 + kc) * 64 + vc] = acc[i];
    }
}

// ---------------- K8: fused MFMA conv + lambda epilogue (cl-reduce inlined) --------
#define SPW 88
#define LD_FRAG(P) __builtin_bit_cast(s16x8, make_int4((P)[0], (P)[2], (P)[4], (P)[6]))
#define STEP(DY, J) do {                                                        \
    const unsigned* pnew_ = xbase + ((DY) + 3) * SPW;                           \
    rw[((J) + 3) & 3][0] = LD_FRAG(pnew_);                                      \
    rw[((J) + 3) & 3][1] = LD_FRAG(pnew_ + 16);                                 \
    int dyn_ = ((DY) + 3 < 22) ? (DY) + 3 : 22;                                 \
    wr[((J) + 3) & 3] = wf[dyn_ * 64 + lane];                                   \
    _Pragma("unroll")                                                           \
    for (int ty_ = 0; ty_ < 4; ty_++) {                                         \
      _Pragma("unroll")                                                         \
      for (int x2_ = 0; x2_ < 2; x2_++) {                                       \
        int t_ = ty_ * 2 + x2_;                                                 \
        acc[t_] = __builtin_amdgcn_mfma_f32_16x16x32_bf16(                      \
            wr[(J) & 3], rw[((J) + ty_) & 3][x2_], acc[t_], 0, 0, 0);           \
      }                                                                         \
    }                                                                           \
  } while (0)

__global__ void __launch_bounds__(256, 4) lambda_main(
    const float* __restrict__ qkv, const float* __restrict__ ascale,
    const float* __restrict__ dshift, const float* __restrict__ clpart,
    const short* __restrict__ wfrag, const float* __restrict__ bl,
    float* __restrict__ out) {
    __shared__ unsigned spack[54 * SPW + 8];
    __shared__ float sck[16];

    int vc = blockIdx.x, b = blockIdx.y, h = blockIdx.z;
    int tid = threadIdx.x;

    if (tid < 16) {   // inline cl_reduce: same mc ascending order -> bit-identical
        float s = 0.f;
        for (int mc2 = 0; mc2 < 16; mc2++)
            s += clpart[(((size_t)b * 16 + mc2) * 16 + tid) * 64 + vc];
        sck[tid] = s + bl[tid];
    }

    float av = ascale[64 + vc], dv = dshift[64 + vc];
    const float* vrow = qkv + ((size_t)b * COUT + 80 + vc) * MPIX;
    for (int i = tid; i < 54 * SPW; i += 256) {
        int y = i / SPW, e = i - y * SPW;
        int iy = h * 32 + y - PADH;
        float f0 = 0.f, f1 = 0.f;
        if ((unsigned)iy < 64u) {
            int ix0 = e - PADH, ix1 = e - PADH + 1;
            if ((unsigned)ix0 < 64u) f0 = fmaf(av, vrow[iy * 64 + ix0], dv);
            if ((unsigned)ix1 < 64u) f1 = fmaf(av, vrow[iy * 64 + ix1], dv);
        }
        spack[i] = (unsigned)f2bf(f0) | ((unsigned)f2bf(f1) << 16);
    }
    if (tid < 8) spack[54 * SPW + tid] = 0u;
    __syncthreads();

    int lane = tid & 63;
    int wv = tid >> 6;
    int px = lane & 15;
    int kg = lane >> 4;
    const s16x8* wf = (const s16x8*)wfrag;

    const unsigned* qtb = (const unsigned*)(qkv + (size_t)b * COUT * MPIX);
    float* ob = out + (size_t)b * 256 * MPIX;

    float sck_l[4];
#pragma unroll
    for (int r = 0; r < 4; r++) sck_l[r] = sck[kg * 4 + r];

#pragma unroll 1
    for (int gg = 0; gg < 2; gg++) {
        int y0 = (gg * 4 + wv) * 4;
        const unsigned* base = &spack[y0 * SPW + px + kg * 8];

#pragma unroll 1
        for (int xh = 0; xh < 2; xh++) {
            const unsigned* xbase = base + xh * 32;
            f32x4 acc[8];
#pragma unroll
            for (int t = 0; t < 8; t++) acc[t] = 0.f;

            s16x8 rw[4][2];
            s16x8 wr[4];
#pragma unroll
            for (int r0 = 0; r0 < 3; r0++) {
                const unsigned* p = xbase + r0 * SPW;
                rw[r0][0] = LD_FRAG(p);
                rw[r0][1] = LD_FRAG(p + 16);
            }
#pragma unroll
            for (int s = 0; s < 3; s++) wr[s] = wf[s * 64 + lane];

#pragma unroll 1
            for (int i8 = 0; i8 < 2; i8++) {
                int dyb = i8 * 8;
                STEP(dyb + 0, 0);
                STEP(dyb + 1, 1);
                STEP(dyb + 2, 2);
                STEP(dyb + 3, 3);
                STEP(dyb + 4, 4);
                STEP(dyb + 5, 5);
                STEP(dyb + 6, 6);
                STEP(dyb + 7, 7);
            }
            STEP(16, 0);
            STEP(17, 1);
            STEP(18, 2);
            STEP(19, 3);
            STEP(20, 4);
            STEP(21, 5);
            STEP(22, 6);

#pragma unroll
            for (int t = 0; t < 8; t++) {
                int ty = t >> 1, x2 = t & 1;
                int m0 = (h * 32 + y0 + ty) * 64 + (xh * 2 + x2) * 16;
                float lam[4];
#pragma unroll
                for (int r = 0; r < 4; r++) lam[r] = acc[t][r] + sck_l[r];
                const unsigned* qp = &qtb[(size_t)(m0 + px) * 64 + kg * 8];
                uint4 qa = *(const uint4*)qp;
                uint4 qb4 = *(const uint4*)(qp + 4);
                unsigned dws[8] = {qa.x, qa.y, qa.z, qa.w, qb4.x, qb4.y, qb4.z, qb4.w};
                float po[4] = {0.f, 0.f, 0.f, 0.f};
#pragma unroll
                for (int d = 0; d < 8; d++) {
                    float q0 = __builtin_bit_cast(float, dws[d] << 16);
                    float q1 = __builtin_bit_cast(float, dws[d] & 0xffff0000u);
                    int i0 = 2 * d, i1 = 2 * d + 1;
                    po[i0 & 3] = fmaf(q0, lam[i0 >> 2], po[i0 & 3]);
                    po[i1 & 3] = fmaf(q1, lam[i1 >> 2], po[i1 & 3]);
                }
#pragma unroll
                for (int n = 0; n < 4; n++) {
                    po[n] += __shfl_xor(po[n], 16);
                    po[n] += __shfl_xor(po[n], 32);
                }
                float sv = (kg == 0) ? po[0] : (kg == 1) ? po[1] : (kg == 2) ? po[2] : po[3];
                ob[(size_t)(kg * 64 + vc) * MPIX + m0 + px] = sv;
            }
        }
    }
}

// ---------------- launch ----------------
extern "C" void kernel_launch(void* const* d_in, const int* in_sizes, int n_in,
                              void* d_out, int out_size, void* d_ws, size_t ws_size,
                              hipStream_t stream) {
    const float* x      = (const float*)d_in[0];
    const float* w_qkv  = (const float*)d_in[1];
    const float* gq     = (const float*)d_in[2];
    const float* bq     = (const float*)d_in[3];
    const float* gv     = (const float*)d_in[4];
    const float* bv     = (const float*)d_in[5];
    const float* wl     = (const float*)d_in[6];
    const float* bl     = (const float*)d_in[7];
    float* out = (float*)d_out;

    float* ws     = (float*)d_ws;
    float* qkv    = ws;                    // 9,437,184 floats (q region holds [m][64c])
    float* ascale = qkv + 9437184;         // 128
    float* dshift = ascale + 128;          // 128
    float* clpart = dshift + 128;          // 262,144
    short* wfrag  = (short*)(clpart + 262144);           // 11,776 halfs
    short* wqf    = (short*)(clpart + 262144 + 5888 + 64); // 36,864 halfs
    float* statpart = (float*)(wqf + 36864);             // 294,912 floats
    float* kpart  = statpart + 294912;     // 16,384
    float* ksm    = kpart + 16384;         // 256

    prep_frags<<<190, 256, 0, stream>>>(w_qkv, wl, wqf, wfrag);
    gemm_qkv<<<dim3(64, 16), 256, 0, stream>>>(x, wqf, qkv, statpart, kpart);
    stats_finalize<<<384, 256, 0, stream>>>(statpart, kpart, gq, bq, gv, bv,
                                            ascale, dshift, ksm);
    cl_bnq<<<dim3(80, 16), 256, 0, stream>>>(qkv, ksm, ascale, dshift, clpart);
    lambda_main<<<dim3(64, 16, 2), 256, 0, stream>>>(qkv, ascale, dshift, clpart, wfrag, bl, out);
}

// Round 20
// 188.881 us; speedup vs baseline: 1.1672x; 1.0215x over previous
//
#include <hip/hip_runtime.h>
#include <math.h>

#define NB    16      // batch
#define CDIM  256
#define COUT  144     // 64 q + 16 k + 64 v
#define MPIX  4096    // 64*64
#define SCOPE 23
#define PADH  11
#define BNEPS 1e-5f

typedef __attribute__((ext_vector_type(4))) float f32x4;
typedef __attribute__((ext_vector_type(8))) short s16x8;

__device__ __forceinline__ unsigned short f2bf(float f) {
    unsigned u = __builtin_bit_cast(unsigned, f);
    unsigned r = (u + 0x7FFFu + ((u >> 16) & 1u)) >> 16;
    return (unsigned short)r;
}

// ---------------- K0: both weight-fragment preps merged ----------------
__global__ void prep_frags(const float* __restrict__ w, const float* __restrict__ wl,
                           short* __restrict__ wqf, short* __restrict__ wfrag) {
    int i = blockIdx.x * 256 + threadIdx.x;
    if (i < 36864) {
        int j = i & 7, lane = (i >> 3) & 63;
        int fi = i >> 9;
        int mf = fi % 9, kc = fi / 9;
        int o = mf * 16 + (lane & 15);
        int c = kc * 32 + (lane >> 4) * 8 + j;
        wqf[i] = (short)f2bf(w[o * 256 + c]);
        return;
    }
    int i2 = i - 36864;
    if (i2 < 23 * 64 * 8) {
        int j = i2 & 7, l = (i2 >> 3) & 63, dy = i2 >> 9;
        int k = l & 15, t = ((l >> 4) << 3) + j;
        float wv = (t < SCOPE) ? wl[k * 529 + dy * 23 + t] : 0.f;
        wfrag[i2] = (short)f2bf(wv);
    }
}

// ---------------- K1: qkv GEMM + fused BN stat partials + softmax denominator ----
__global__ void __launch_bounds__(256, 4) gemm_qkv(const float* __restrict__ x,
                                                   const short* __restrict__ wqf,
                                                   float* __restrict__ qkv,
                                                   float* __restrict__ statpart,
                                                   float* __restrict__ kpart) {
    __shared__ unsigned pk[16 * 65];
    __shared__ float ssum[4][144], ssq[4][144];
    __shared__ float sse[4][16];
    int mt = blockIdx.x, b = blockIdx.y;
    int m0 = mt * 64;
    int tid = threadIdx.x;
    int px64 = tid & 63, c2b = tid >> 6;
    int lane = tid & 63, wv = tid >> 6;
    int pxl = lane & 15, kgq = lane >> 4;
    const float* xb = x + (size_t)b * CDIM * MPIX;
    float* qtb = qkv + (size_t)b * COUT * MPIX;
    const s16x8* wfv = (const s16x8*)wqf;

    f32x4 acc[9];
#pragma unroll
    for (int mf = 0; mf < 9; mf++) acc[mf] = 0.f;

#pragma unroll 1
    for (int kc = 0; kc < 8; kc++) {
        if (kc > 0) __syncthreads();
#pragma unroll
        for (int it = 0; it < 4; it++) {
            int c2 = c2b + it * 4;
            float x0 = xb[(size_t)(kc * 32 + 2 * c2) * MPIX + m0 + px64];
            float x1 = xb[(size_t)(kc * 32 + 2 * c2 + 1) * MPIX + m0 + px64];
            pk[c2 * 65 + px64] = (unsigned)f2bf(x0) | ((unsigned)f2bf(x1) << 16);
        }
        __syncthreads();
        const unsigned* bp = &pk[kgq * 4 * 65 + wv * 16 + pxl];
        int4 bi = make_int4(bp[0], bp[65], bp[130], bp[195]);
        s16x8 bf = __builtin_bit_cast(s16x8, bi);
#pragma unroll
        for (int mf = 0; mf < 9; mf++) {
            s16x8 af = wfv[(kc * 9 + mf) * 64 + lane];
            acc[mf] = __builtin_amdgcn_mfma_f32_16x16x32_bf16(af, bf, acc[mf], 0, 0, 0);
        }
    }

    int m = m0 + wv * 16 + pxl;
#pragma unroll
    for (int mf = 0; mf < 9; mf++) {
#pragma unroll
        for (int r = 0; r < 4; r++) {
            int o = mf * 16 + kgq * 4 + r;
            if (mf < 4) qtb[(size_t)m * 64 + o] = acc[mf][r];
            else qkv[((size_t)b * COUT + o) * MPIX + m] = acc[mf][r];
        }
    }

#pragma unroll
    for (int mf = 0; mf < 9; mf++) {
#pragma unroll
        for (int r = 0; r < 4; r++) {
            float s = acc[mf][r];
            float s2 = s * s;
#pragma unroll
            for (int off = 1; off < 16; off <<= 1) {
                s += __shfl_xor(s, off);
                s2 += __shfl_xor(s2, off);
            }
            if (mf == 4) {
                float e = __expf(acc[mf][r]);
#pragma unroll
                for (int off = 1; off < 16; off <<= 1) e += __shfl_xor(e, off);
                if (pxl == 0) sse[wv][kgq * 4 + r] = e;
            }
            if (pxl == 0) {
                int ch = mf * 16 + kgq * 4 + r;
                ssum[wv][ch] = s;
                ssq[wv][ch] = s2;
            }
        }
    }
    __syncthreads();
    if (tid < 144) {
        float s = ssum[0][tid] + ssum[1][tid] + ssum[2][tid] + ssum[3][tid];
        float s2 = ssq[0][tid] + ssq[1][tid] + ssq[2][tid] + ssq[3][tid];
        size_t idx = (((size_t)tid * 16 + b) * 64 + mt) * 2;
        statpart[idx + 0] = s;
        statpart[idx + 1] = s2;
    }
    if (tid >= 144 && tid < 160) {
        int kc = tid - 144;
        float e = sse[0][kc] + sse[1][kc] + sse[2][kc] + sse[3][kc];
        kpart[((size_t)kc * 16 + b) * 64 + mt] = e;
    }
}

// ---------------- K3: finalize — blocks 0..127 BN; 128..383 softmax rinv ----------
__global__ void stats_finalize(const float* __restrict__ statpart,
                               const float* __restrict__ kpart,
                               const float* __restrict__ gq, const float* __restrict__ bq,
                               const float* __restrict__ gv, const float* __restrict__ bv,
                               float* __restrict__ ascale, float* __restrict__ dshift,
                               float* __restrict__ ksm) {
    int tid = threadIdx.x;
    if (blockIdx.x >= 128) {
        int id = blockIdx.x - 128;
        if (tid < 64) {
            float s = kpart[(size_t)id * 64 + tid];
#pragma unroll
            for (int off = 32; off > 0; off >>= 1) s += __shfl_down(s, off);
            if (tid == 0) ksm[id] = 1.0f / s;
        }
        return;
    }
    int sch = blockIdx.x;
    int gch = (sch < 64) ? sch : sch + 16;
    const float* sp = statpart + (size_t)gch * 1024 * 2;
    float s = 0.f, s2 = 0.f;
    for (int i = tid; i < 1024; i += 256) {
        s += sp[i * 2 + 0];
        s2 += sp[i * 2 + 1];
    }
#pragma unroll
    for (int off = 32; off > 0; off >>= 1) {
        s += __shfl_down(s, off);
        s2 += __shfl_down(s2, off);
    }
    __shared__ float red[8];
    int wid = tid >> 6, lane = tid & 63;
    if (lane == 0) { red[wid * 2] = s; red[wid * 2 + 1] = s2; }
    __syncthreads();
    if (tid == 0) {
        float ts = 0.f, ts2 = 0.f;
#pragma unroll
        for (int w2 = 0; w2 < 4; w2++) { ts += red[w2 * 2]; ts2 += red[w2 * 2 + 1]; }
        const float invN = 1.0f / 65536.0f;
        float mean = ts * invN;
        float var = ts2 * invN - mean * mean;
        float g = (sch < 64) ? gq[sch] : gv[sch - 64];
        float be = (sch < 64) ? bq[sch] : bv[sch - 64];
        float a = g * rsqrtf(var + BNEPS);
        ascale[sch] = a;
        dshift[sch] = be - mean * a;
    }
}

// ---------------- K5: merged cl_partial (roles 0..15) + bnq_t (roles 16..79) --------
__global__ void __launch_bounds__(256) cl_bnq(float* __restrict__ qkv,
                                              const float* __restrict__ ksm,
                                              const float* __restrict__ ascale,
                                              const float* __restrict__ dshift,
                                              float* __restrict__ clpart) {
    __shared__ float smem[128 * 65 + 16 * 132 + 16];   // 41.9 KB union
    int role = blockIdx.x, b = blockIdx.y;
    int tid = threadIdx.x;

    if (role >= 16) {
        float (*sv)[65] = (float(*)[65])smem;
        int mt = role - 16;
        int m0 = mt * 64;
        float* qb = qkv + (size_t)b * COUT * MPIX;
        int c = tid & 63, mg = tid >> 6;
        float a = ascale[c], d = dshift[c];
#pragma unroll
        for (int i = 0; i < 16; i++) {
            int m = mg * 16 + i;
            sv[m][c] = fmaf(a, qb[(size_t)(m0 + m) * 64 + c], d);
        }
        __syncthreads();
        int m = tid >> 2, jb = (tid & 3) * 8;
        unsigned dw[8];
#pragma unroll
        for (int j = 0; j < 8; j++) {
            int cc = jb * 2 + 2 * j;
            dw[j] = (unsigned)f2bf(sv[m][cc]) | ((unsigned)f2bf(sv[m][cc + 1]) << 16);
        }
        unsigned* dst = (unsigned*)qb + (size_t)(m0 + m) * 64 + jb;
        *(uint4*)dst = make_uint4(dw[0], dw[1], dw[2], dw[3]);
        *(uint4*)(dst + 4) = make_uint4(dw[4], dw[5], dw[6], dw[7]);
        return;
    }

    float (*vsT)[65] = (float(*)[65])smem;
    float (*pk2)[132] = (float(*)[132])(smem + 128 * 65);
    float* skr = smem + 128 * 65 + 16 * 132;
    int mc = role;
    int m0 = mc * 256;
    int vc = tid & 63, kg = tid >> 6;
    if (tid < 16) skr[tid] = ksm[(size_t)tid * 16 + b];
    float acc[4] = {0.f, 0.f, 0.f, 0.f};
    for (int half = 0; half < 2; half++) {
        int mh = m0 + half * 128;
        __syncthreads();
        for (int i = tid; i < 64 * 128; i += 256) {
            int r = i >> 7, c = i & 127;
            vsT[c][r] = fmaf(ascale[64 + r], qkv[((size_t)b * COUT + 80 + r) * MPIX + mh + c],
                             dshift[64 + r]);
        }
        for (int i = tid; i < 16 * 128; i += 256) {
            int kc = i >> 7, mm = i & 127;
            pk2[kc][mm] = __expf(qkv[((size_t)b * COUT + 64 + kc) * MPIX + mh + mm]) * skr[kc];
        }
        __syncthreads();
        for (int mm = 0; mm < 128; mm++) {
            float vv = vsT[mm][vc];
#pragma unroll
            for (int i = 0; i < 4; i++) {
                int kc = kg * 4 + i;
                acc[i] = fmaf(pk2[kc][mm], vv, acc[i]);
            }
        }
    }
#pragma unroll
    for (int i = 0; i < 4; i++) {
        int kc = kg * 4 + i;
        clpart[(((size_t)b * 16 + mc) * 16 + kc) * 64 + vc] = acc[i];
    }
}

// ---------------- K8: fused MFMA conv + lambda epilogue (reduce-scatter shuffles) ---
#define SPW 88
#define LD_FRAG(P) __builtin_bit_cast(s16x8, make_int4((P)[0], (P)[2], (P)[4], (P)[6]))
#define STEP(DY, J) do {                                                        \
    const unsigned* pnew_ = xbase + ((DY) + 3) * SPW;                           \
    rw[((J) + 3) & 3][0] = LD_FRAG(pnew_);                                      \
    rw[((J) + 3) & 3][1] = LD_FRAG(pnew_ + 16);                                 \
    int dyn_ = ((DY) + 3 < 22) ? (DY) + 3 : 22;                                 \
    wr[((J) + 3) & 3] = wf[dyn_ * 64 + lane];                                   \
    _Pragma("unroll")                                                           \
    for (int ty_ = 0; ty_ < 4; ty_++) {                                         \
      _Pragma("unroll")                                                         \
      for (int x2_ = 0; x2_ < 2; x2_++) {                                       \
        int t_ = ty_ * 2 + x2_;                                                 \
        acc[t_] = __builtin_amdgcn_mfma_f32_16x16x32_bf16(                      \
            wr[(J) & 3], rw[((J) + ty_) & 3][x2_], acc[t_], 0, 0, 0);           \
      }                                                                         \
    }                                                                           \
  } while (0)

__global__ void __launch_bounds__(256, 4) lambda_main(
    const float* __restrict__ qkv, const float* __restrict__ ascale,
    const float* __restrict__ dshift, const float* __restrict__ clpart,
    const short* __restrict__ wfrag, const float* __restrict__ bl,
    float* __restrict__ out) {
    __shared__ unsigned spack[54 * SPW + 8];
    __shared__ float sck[16];

    int vc = blockIdx.x, b = blockIdx.y, h = blockIdx.z;
    int tid = threadIdx.x;

    if (tid < 16) {   // inline cl_reduce: same mc ascending order
        float s = 0.f;
        for (int mc2 = 0; mc2 < 16; mc2++)
            s += clpart[(((size_t)b * 16 + mc2) * 16 + tid) * 64 + vc];
        sck[tid] = s + bl[tid];
    }

    float av = ascale[64 + vc], dv = dshift[64 + vc];
    const float* vrow = qkv + ((size_t)b * COUT + 80 + vc) * MPIX;
    for (int i = tid; i < 54 * SPW; i += 256) {
        int y = i / SPW, e = i - y * SPW;
        int iy = h * 32 + y - PADH;
        float f0 = 0.f, f1 = 0.f;
        if ((unsigned)iy < 64u) {
            int ix0 = e - PADH, ix1 = e - PADH + 1;
            if ((unsigned)ix0 < 64u) f0 = fmaf(av, vrow[iy * 64 + ix0], dv);
            if ((unsigned)ix1 < 64u) f1 = fmaf(av, vrow[iy * 64 + ix1], dv);
        }
        spack[i] = (unsigned)f2bf(f0) | ((unsigned)f2bf(f1) << 16);
    }
    if (tid < 8) spack[54 * SPW + tid] = 0u;
    __syncthreads();

    int lane = tid & 63;
    int wv = tid >> 6;
    int px = lane & 15;
    int kg = lane >> 4;
    const s16x8* wf = (const s16x8*)wfrag;

    const unsigned* qtb = (const unsigned*)(qkv + (size_t)b * COUT * MPIX);
    float* ob = out + (size_t)b * 256 * MPIX;

    float sck_l[4];
#pragma unroll
    for (int r = 0; r < 4; r++) sck_l[r] = sck[kg * 4 + r];
    int kb0 = kg & 1, kb2 = kg & 2;

#pragma unroll 1
    for (int gg = 0; gg < 2; gg++) {
        int y0 = (gg * 4 + wv) * 4;
        const unsigned* base = &spack[y0 * SPW + px + kg * 8];

#pragma unroll 1
        for (int xh = 0; xh < 2; xh++) {
            const unsigned* xbase = base + xh * 32;
            f32x4 acc[8];
#pragma unroll
            for (int t = 0; t < 8; t++) acc[t] = 0.f;

            s16x8 rw[4][2];
            s16x8 wr[4];
#pragma unroll
            for (int r0 = 0; r0 < 3; r0++) {
                const unsigned* p = xbase + r0 * SPW;
                rw[r0][0] = LD_FRAG(p);
                rw[r0][1] = LD_FRAG(p + 16);
            }
#pragma unroll
            for (int s = 0; s < 3; s++) wr[s] = wf[s * 64 + lane];

#pragma unroll 1
            for (int i8 = 0; i8 < 2; i8++) {
                int dyb = i8 * 8;
                STEP(dyb + 0, 0);
                STEP(dyb + 1, 1);
                STEP(dyb + 2, 2);
                STEP(dyb + 3, 3);
                STEP(dyb + 4, 4);
                STEP(dyb + 5, 5);
                STEP(dyb + 6, 6);
                STEP(dyb + 7, 7);
            }
            STEP(16, 0);
            STEP(17, 1);
            STEP(18, 2);
            STEP(19, 3);
            STEP(20, 4);
            STEP(21, 5);
            STEP(22, 6);

#pragma unroll
            for (int t = 0; t < 8; t++) {
                int ty = t >> 1, x2 = t & 1;
                int m0 = (h * 32 + y0 + ty) * 64 + (xh * 2 + x2) * 16;
                float lam[4];
#pragma unroll
                for (int r = 0; r < 4; r++) lam[r] = acc[t][r] + sck_l[r];
                const unsigned* qp = &qtb[(size_t)(m0 + px) * 64 + kg * 8];
                uint4 qa = *(const uint4*)qp;
                uint4 qb4 = *(const uint4*)(qp + 4);
                unsigned dws[8] = {qa.x, qa.y, qa.z, qa.w, qb4.x, qb4.y, qb4.z, qb4.w};
                float po[4] = {0.f, 0.f, 0.f, 0.f};
#pragma unroll
                for (int d = 0; d < 8; d++) {
                    float q0 = __builtin_bit_cast(float, dws[d] << 16);
                    float q1 = __builtin_bit_cast(float, dws[d] & 0xffff0000u);
                    int i0 = 2 * d, i1 = 2 * d + 1;
                    po[i0 & 3] = fmaf(q0, lam[i0 >> 2], po[i0 & 3]);
                    po[i1 & 3] = fmaf(q1, lam[i1 >> 2], po[i1 & 3]);
                }
                // 2-step reduce-scatter across kg groups: 3 shfl + 3 add
                // step 1 (xor 16): send the low/high slots I don't keep
                float s0 = kb0 ? po[0] : po[1];
                float s1 = kb0 ? po[2] : po[3];
                float r0 = __shfl_xor(s0, 16);
                float r1 = __shfl_xor(s1, 16);
                float alo = (kb0 ? po[1] : po[0]) + r0;   // slot kb0, over kg-pair
                float bhi = (kb0 ? po[3] : po[2]) + r1;   // slot 2|kb0, over kg-pair
                // step 2 (xor 32): send the half I don't keep
                float s2 = kb2 ? alo : bhi;
                float r2 = __shfl_xor(s2, 32);
                float fin = (kb2 ? bhi : alo) + r2;       // = total of slot kg
                ob[(size_t)(kg * 64 + vc) * MPIX + m0 + px] = fin;
            }
        }
    }
}

// ---------------- launch ----------------
extern "C" void kernel_launch(void* const* d_in, const int* in_sizes, int n_in,
                              void* d_out, int out_size, void* d_ws, size_t ws_size,
                              hipStream_t stream) {
    const float* x      = (const float*)d_in[0];
    const float* w_qkv  = (const float*)d_in[1];
    const float* gq     = (const float*)d_in[2];
    const float* bq     = (const float*)d_in[3];
    const float* gv     = (const float*)d_in[4];
    const float* bv     = (const float*)d_in[5];
    const float* wl     = (const float*)d_in[6];
    const float* bl     = (const float*)d_in[7];
    float* out = (float*)d_out;

    float* ws     = (float*)d_ws;
    float* qkv    = ws;                    // 9,437,184 floats (q region holds [m][64c])
    float* ascale = qkv + 9437184;         // 128
    float* dshift = ascale + 128;          // 128
    float* clpart = dshift + 128;          // 262,144
    short* wfrag  = (short*)(clpart + 262144);             // 11,776 halfs
    short* wqf    = (short*)(clpart + 262144 + 5888 + 64); // 36,864 halfs
    float* statpart = (float*)(wqf + 36864);               // 294,912 floats
    float* kpart  = statpart + 294912;     // 16,384
    float* ksm    = kpart + 16384;         // 256

    prep_frags<<<190, 256, 0, stream>>>(w_qkv, wl, wqf, wfrag);
    gemm_qkv<<<dim3(64, 16), 256, 0, stream>>>(x, wqf, qkv, statpart, kpart);
    stats_finalize<<<384, 256, 0, stream>>>(statpart, kpart, gq, bq, gv, bv,
                                            ascale, dshift, ksm);
    cl_bnq<<<dim3(80, 16), 256, 0, stream>>>(qkv, ksm, ascale, dshift, clpart);
    lambda_main<<<dim3(64, 16, 2), 256, 0, stream>>>(qkv, ascale, dshift, clpart, wfrag, bl, out);
}